// Round 5
// baseline (393.789 us; speedup 1.0000x reference)
//
#include <hip/hip_runtime.h>
#include <math.h>

// All reference tensors are float32 -> inputs are const float*, output float*.

constexpr int Bn = 4;          // batch

typedef __attribute__((ext_vector_type(8))) short short8;   // 8 bf16 (4 VGPRs)
typedef __attribute__((ext_vector_type(4))) short s16x4;    // 4 bf16 (8 B)
typedef __attribute__((ext_vector_type(4))) float f32x4;    // MFMA 16x16 acc

static __device__ __forceinline__ short f2b(float f){
  union { float f; unsigned u; } v; v.f = f;
  unsigned r = v.u + 0x7fffu + ((v.u >> 16) & 1u);   // RNE
  return (short)(r >> 16);
}

// ---- workspace layout (float offsets; all multiples of 4 -> 16B aligned) ----
constexpr size_t OFF_CUR   = 0;                         // 4*16384*64 f32 NHWC (per level, reused)
constexpr size_t OFF_DC    = OFF_CUR  + 4194304;        // 4*16384*64 f32 NHWC
constexpr size_t OFF_T0    = OFF_DC   + 4194304;        // fuse outputs, CHW [b][o][p]
constexpr size_t OFF_T1    = OFF_T0   + 4194304;
constexpr size_t OFF_T2    = OFF_T1   + 1048576;
constexpr size_t OFF_T3    = OFF_T2   + 262144;
constexpr size_t OFF_WSUMT = OFF_T3   + 65536;          // bf16 [4][64][64]   kdim=c
constexpr size_t OFF_DCWT  = OFF_WSUMT + 8192;          // bf16 [4][64][576]  kdim=k*64+c
constexpr size_t OFF_OWT   = OFF_DCWT  + 73728;         // bf16 [4][32][576]  kdim=k*64+c
constexpr size_t OFF_SUMS  = OFF_OWT   + 36864;         // f32 [4][64 slots][256]
constexpr size_t OFF_G     = OFF_SUMS  + 65536;         // f32 [4][4][64]
constexpr size_t OFF_TKT   = OFF_G     + 1024;          // 4 uint tickets

// ---- prep: reorder weights to bf16 (N-major, kdim=k*64+c), cumulative fuse, zero sums+tickets ----
__global__ void prep_k(const float* __restrict__ dc_w, const float* __restrict__ off_w,
                       const float* __restrict__ fuse_w, float* __restrict__ ws){
  int i = blockIdx.x * 256 + threadIdx.x;
  short* dcwT  = (short*)(ws + OFF_DCWT);
  short* owT   = (short*)(ws + OFF_OWT);
  short* wsumT = (short*)(ws + OFF_WSUMT);
  if (i < 147456){
    int oc = i / 576, r = i % 576, k = r >> 6, c = r & 63;      // oc = l*64+o
    dcwT[i] = f2b(dc_w[(oc*64 + c)*9 + k]);
  } else if (i < 147456 + 73728){
    int t = i - 147456;
    int lm = t / 576, l = lm >> 5, m = lm & 31, r = t % 576, k = r >> 6, c = r & 63;
    owT[t] = (m < 18) ? f2b(off_w[((l*18 + m)*64 + c)*9 + k]) : (short)0;
  } else if (i < 147456 + 73728 + 16384){
    int t = i - (147456 + 73728);
    int l = t / 4096, r = t % 4096, o = r / 64, c = r % 64;
    float s = 0.f;
    for (int jl = 0; jl <= l; jl++) s += fuse_w[o*256 + jl*64 + c];
    wsumT[t] = f2b(s);
  } else if (i < 147456 + 73728 + 16384 + 65536){
    ws[OFF_SUMS + (i - (147456 + 73728 + 16384))] = 0.f;
  } else if (i < 147456 + 73728 + 16384 + 65536 + 4){
    ((unsigned*)(ws + OFF_TKT))[i - (147456 + 73728 + 16384 + 65536)] = 0u;
  }
}

// ---- convert x: NCHW -> NHWC via LDS-tiled transpose (coalesced both sides) ----
__global__ __launch_bounds__(256) void cvt_k(const float* __restrict__ x, float* __restrict__ cur){
  __shared__ float t[64][65];
  int tile = blockIdx.x;                 // 1024 tiles: b(4) x 256 pixel-groups
  int b = tile >> 8, p0 = (tile & 255) << 6;
  int tx = threadIdx.x & 63, ty = threadIdx.x >> 6;
  #pragma unroll
  for (int c = ty; c < 64; c += 4)
    t[c][tx] = x[(((size_t)(b << 6) + c) << 14) + p0 + tx];
  __syncthreads();
  #pragma unroll
  for (int pp = ty; pp < 64; pp += 4)
    cur[(((size_t)(b << 14)) + p0 + pp) * 64 + tx] = t[tx][pp];
}

// ---- fused: offset conv (MFMA) + bilinear sampling + deform GEMM (MFMA) + SE (last block) ----
// 4 waves per block, 16 pixels; kdim = tap*64 + channel; 16 lanes cover one tap (float4/lane)
template<int H, int LVL>
__global__ __launch_bounds__(256, 6) void deform_k(
    const float* __restrict__ cur, const float* __restrict__ ws_all,
    const float* __restrict__ off_bias, const float* __restrict__ dc_bias,
    const float* __restrict__ se_w1, const float* __restrict__ se_b1,
    const float* __restrict__ se_w2, const float* __restrict__ se_b2,
    float* __restrict__ dc, float* __restrict__ sums,
    float* __restrict__ g_out, unsigned* __restrict__ tkt){
  constexpr int W = H, P = H * W;
  __shared__ __align__(16) short valA[16][584];   // bf16, kdim-major rows, pad->584
  __shared__ float offs[16][18];
  __shared__ int2   tapA[144];                    // {clamped idx, fp mask}
  __shared__ float4 tapW[144];                    // bilinear corner weights
  __shared__ int4   tapI[144];                    // clamped corner indices
  __shared__ int isLast;
  const short* owt = (const short*)(ws_all + OFF_OWT) + LVL * 32 * 576;
  const short* dcw = (const short*)(ws_all + OFF_DCWT) + (size_t)LVL * 64 * 576;
  const int tid = threadIdx.x;
  const int wave = tid >> 6, lane = tid & 63;
  const int c0 = lane & 15, quad = lane >> 4, q4 = quad * 4;
  const int tq = lane >> 4, u = lane & 15;        // staging: tap-in-group, channel-chunk
  const int pix0 = blockIdx.x * 16;
  const int b = pix0 / P, pb = pix0 % P;
  const float* curb = cur + (size_t)b * P * 64;

  // A0: per-tap patch index/mask
  if (tid < 144){
    int p = tid / 9, k = tid % 9;
    int pp = pb + p, h = pp / W, w = pp % W;
    int yy = h + k/3 - 1, xx = w + k%3 - 1;
    bool valid = (yy >= 0) & (yy < H) & (xx >= 0) & (xx < W);
    tapA[tid] = make_int2(valid ? (yy * W + xx) : 0, valid ? __float_as_int(1.f) : 0);
  }
  __syncthreads();

  // A1: stage zero-padded patches, bf16; 4 taps per wave-iteration, float4 per lane
  #pragma unroll
  for (int gidx = 0; gidx < 9; gidx++){
    int t = wave*36 + gidx*4 + tq;
    int p = t / 9, k = t - p*9;
    int2 ta = tapA[t];
    float m = __int_as_float(ta.y);
    float4 v = *(const float4*)&curb[(size_t)ta.x*64 + u*4];
    s16x4 s4 = {f2b(v.x*m), f2b(v.y*m), f2b(v.z*m), f2b(v.w*m)};
    *(s16x4*)&valA[p][k*64 + u*4] = s4;
  }
  __syncthreads();

  // B: offset conv via MFMA [16x576]@[576x32]; waves 0/1 take cols 16w..16w+15
  if (wave < 2){
    f32x4 oacc = {0,0,0,0};
    #pragma unroll
    for (int kb = 0; kb < 18; kb++){
      short8 a  = *(const short8*)&valA[c0][kb*32 + quad*8];
      short8 bf = *(const short8*)&owt[(wave*16 + c0)*576 + kb*32 + quad*8];
      oacc = __builtin_amdgcn_mfma_f32_16x16x32_bf16(a, bf, oacc, 0, 0, 0);
    }
    int comp = wave*16 + c0;
    if (comp < 18){
      float ob = off_bias[LVL*18 + comp];
      #pragma unroll
      for (int r = 0; r < 4; r++) offs[q4 + r][comp] = oacc[r] + ob;
    }
  }
  __syncthreads();

  // C0: per-tap bilinear weights + clamped corner indices
  if (tid < 144){
    int p = tid / 9, k = tid % 9;
    int pp = pb + p, h = pp / W, w = pp % W;
    float py = (float)(h + k/3 - 1) + offs[p][2*k];
    float px = (float)(w + k%3 - 1) + offs[p][2*k + 1];
    float y0f = floorf(py), x0f = floorf(px);
    float fy = py - y0f, fx = px - x0f;
    int y0 = (int)y0f, x0 = (int)x0f, y1 = y0 + 1, x1 = x0 + 1;
    bool vy0 = (y0 >= 0) & (y0 < H), vy1 = (y1 >= 0) & (y1 < H);
    bool vx0 = (x0 >= 0) & (x0 < W), vx1 = (x1 >= 0) & (x1 < W);
    int y0c = min(max(y0, 0), H-1), y1c = min(max(y1, 0), H-1);
    int x0c = min(max(x0, 0), W-1), x1c = min(max(x1, 0), W-1);
    float gy = 1.f - fy, gx = 1.f - fx;
    tapW[tid] = make_float4((vy0 & vx0) ? gy*gx : 0.f,
                            (vy0 & vx1) ? gy*fx : 0.f,
                            (vy1 & vx0) ? fy*gx : 0.f,
                            (vy1 & vx1) ? fy*fx : 0.f);
    tapI[tid] = make_int4(y0c*W + x0c, y0c*W + x1c, y1c*W + x0c, y1c*W + x1c);
  }
  __syncthreads();

  // C1: sample; 4 taps per wave-iteration, float4 per lane; overwrite valA
  #pragma unroll
  for (int gidx = 0; gidx < 9; gidx++){
    int t = wave*36 + gidx*4 + tq;
    int p = t / 9, k = t - p*9;
    float4 wv = tapW[t];
    int4   iv = tapI[t];
    float4 a0 = *(const float4*)&curb[(size_t)iv.x*64 + u*4];
    float4 a1 = *(const float4*)&curb[(size_t)iv.y*64 + u*4];
    float4 a2 = *(const float4*)&curb[(size_t)iv.z*64 + u*4];
    float4 a3 = *(const float4*)&curb[(size_t)iv.w*64 + u*4];
    float vx = wv.x*a0.x + wv.y*a1.x + wv.z*a2.x + wv.w*a3.x;
    float vy = wv.x*a0.y + wv.y*a1.y + wv.z*a2.y + wv.w*a3.y;
    float vz = wv.x*a0.z + wv.y*a1.z + wv.z*a2.z + wv.w*a3.z;
    float vw = wv.x*a0.w + wv.y*a1.w + wv.z*a2.w + wv.w*a3.w;
    s16x4 s4 = {f2b(vx), f2b(vy), f2b(vz), f2b(vw)};
    *(s16x4*)&valA[p][k*64 + u*4] = s4;
  }
  __syncthreads();

  // D: deform GEMM [16x576]@[576x64]; wave w takes cols 16w..16w+15
  const int n = wave*16 + c0;
  float bt = dc_bias[LVL*64 + n];
  f32x4 acc = {bt, bt, bt, bt};
  #pragma unroll
  for (int kb = 0; kb < 18; kb++){
    short8 a  = *(const short8*)&valA[c0][kb*32 + quad*8];
    short8 bf = *(const short8*)&dcw[n*576 + kb*32 + quad*8];
    acc = __builtin_amdgcn_mfma_f32_16x16x32_bf16(a, bf, acc, 0, 0, 0);
  }
  float* dcb = dc + (size_t)pix0 * 64;
  #pragma unroll
  for (int r = 0; r < 4; r++) dcb[(q4 + r)*64 + n] = acc[r];
  float s = acc[0] + acc[1] + acc[2] + acc[3];
  s += __shfl_xor(s, 16);
  s += __shfl_xor(s, 32);
  if (quad == 0) atomicAdd(&sums[(LVL*64 + (blockIdx.x & 63))*256 + (b << 6) + n], s);

  // E: last block computes SE gates (ticket; sums are device-scope atomics)
  __syncthreads();
  if (tid == 0){
    __threadfence();
    unsigned old = atomicAdd(&tkt[LVL], 1u);
    isLast = (old == (unsigned)(gridDim.x - 1));
  }
  __syncthreads();
  if (isLast){
    __threadfence();
    float* ms = (float*)tapW;   // 1024 B
    float* hs = (float*)tapI;   // 64 B
    float ss = 0.f;
    for (int slot = 0; slot < 64; slot++) ss += sums[(LVL*64 + slot)*256 + tid];
    ms[tid] = ss / (float)P;
    __syncthreads();
    if (tid < 16){
      int bb = tid >> 2, r = tid & 3;
      float a = se_b1[LVL*4 + r];
      for (int c = 0; c < 64; c++) a += ms[bb*64 + c] * se_w1[(LVL*4 + r)*64 + c];
      hs[tid] = fmaxf(a, 0.f);
    }
    __syncthreads();
    int bb = tid >> 6, c = tid & 63;
    float a = se_b2[LVL*64 + c];
    for (int r = 0; r < 4; r++) a += hs[bb*4 + r] * se_w2[(LVL*64 + c)*4 + r];
    g_out[LVL*256 + tid] = 1.f / (1.f + expf(-a));
  }
}

// ---- fuse + gate + downsample: (dc*g) @ Wsum_l -> tmp_l (CHW); 2x2 avg pool -> cur_{l+1} ----
template<int W, int LVL>
__global__ __launch_bounds__(256) void fuse_gd_k(
    const float* __restrict__ dcv, const float* __restrict__ g,
    const float* __restrict__ ws_all, float* __restrict__ tmp, float* __restrict__ curn){
  constexpr int P = W * W;
  constexpr bool POOL = (LVL < 3);
  __shared__ __align__(16) float fS[64][68];      // gated fp32 values, pad 64->68
  const short* wsl = (const short*)(ws_all + OFF_WSUMT) + LVL * 4096;
  const int tid = threadIdx.x, wave = tid >> 6, lane = tid & 63;
  const int c0 = lane & 15, quad = lane >> 4, q4 = quad * 4;
  int b, rp = 0, cs = 0;
  if (POOL){
    constexpr int tilesPerB = P / 64, tilesPerRow = W / 32;
    b = blockIdx.x / tilesPerB;
    int r = blockIdx.x % tilesPerB;
    rp = r / tilesPerRow; cs = r % tilesPerRow;
  } else {
    b = (blockIdx.x * 64) / P;
  }
  // stage gated fp32 values
  float4 g4 = *(const float4*)&g[LVL*256 + (b << 6) + c0*4];
  #pragma unroll
  for (int i = 0; i < 4; i++){
    int lp = wave*16 + (lane >> 4) + i*4;
    size_t gpix = POOL ? ((size_t)b*P + (size_t)(2*rp + (lp >> 5))*W + cs*32 + (lp & 31))
                       : ((size_t)blockIdx.x*64 + lp);
    float4 d = *(const float4*)&dcv[gpix*64 + c0*4];
    float4 v = make_float4(d.x*g4.x, d.y*g4.y, d.z*g4.z, d.w*g4.w);
    *(float4*)&fS[lp][c0*4] = v;
  }
  __syncthreads();
  // fuse MFMA [16x64]@[64x64] per wave
  f32x4 acc[4] = {{0,0,0,0},{0,0,0,0},{0,0,0,0},{0,0,0,0}};
  #pragma unroll
  for (int kb = 0; kb < 2; kb++){
    float4 lo = *(const float4*)&fS[wave*16 + c0][kb*32 + quad*8];
    float4 hi = *(const float4*)&fS[wave*16 + c0][kb*32 + quad*8 + 4];
    short8 a = {f2b(lo.x), f2b(lo.y), f2b(lo.z), f2b(lo.w),
                f2b(hi.x), f2b(hi.y), f2b(hi.z), f2b(hi.w)};
    #pragma unroll
    for (int t = 0; t < 4; t++){
      short8 bf = *(const short8*)&wsl[(t*16 + c0)*64 + kb*32 + quad*8];
      acc[t] = __builtin_amdgcn_mfma_f32_16x16x32_bf16(a, bf, acc[t], 0, 0, 0);
    }
  }
  #pragma unroll
  for (int t = 0; t < 4; t++){
    int n = t*16 + c0;
    size_t plane = ((size_t)(b << 6) + n) * P;
    size_t pix = POOL ? ((size_t)(2*rp + (wave >> 1))*W + cs*32 + (wave & 1)*16 + q4)
                      : ((size_t)(blockIdx.x*64) - (size_t)b*P + wave*16 + q4);
    *(f32x4*)&tmp[plane + pix] = acc[t];
  }
  // 2x2 avg pool of gated values -> next level input (NHWC)
  if constexpr (POOL){
    int j = tid >> 4, uu = tid & 15;
    float4 p0 = *(const float4*)&fS[2*j][uu*4];
    float4 p1 = *(const float4*)&fS[2*j + 1][uu*4];
    float4 p2 = *(const float4*)&fS[32 + 2*j][uu*4];
    float4 p3 = *(const float4*)&fS[33 + 2*j][uu*4];
    float4 av = make_float4(0.25f*(p0.x + p1.x + p2.x + p3.x),
                            0.25f*(p0.y + p1.y + p2.y + p3.y),
                            0.25f*(p0.z + p1.z + p2.z + p3.z),
                            0.25f*(p0.w + p1.w + p2.w + p3.w));
    *(float4*)&curn[((size_t)b*(P/4) + (size_t)rp*(W/2) + cs*16 + j)*64 + uu*4] = av;
  }
}

// ---- final: 4x bilinear upsample (CHW planes) + sum + fuse bias -> f32 NCHW ----
__global__ void final_k(const float* __restrict__ ws_all, const float* __restrict__ fuse_bias,
                        float* __restrict__ out){
  int i = blockIdx.x * 256 + threadIdx.x;
  int w = i & 127, h = (i >> 7) & 127, o = (i >> 14) & 63, b = i >> 20;
  float acc = fuse_bias[o] + ws_all[OFF_T0 + (((size_t)(b << 6) + o) << 14) + (h << 7) + w];
  const float* tarr[3] = {ws_all + OFF_T1, ws_all + OFF_T2, ws_all + OFF_T3};
  #pragma unroll
  for (int li = 0; li < 3; li++){
    int l = li + 1, Hl = 128 >> l;
    float scale = 1.0f / (float)(1 << l);
    float sy = fminf(fmaxf((h + 0.5f)*scale - 0.5f, 0.f), (float)(Hl - 1));
    float sx = fminf(fmaxf((w + 0.5f)*scale - 0.5f, 0.f), (float)(Hl - 1));
    int y0 = (int)sy, x0 = (int)sx;
    float fy = sy - y0, fx = sx - x0;
    int y1 = min(y0 + 1, Hl - 1), x1 = min(x0 + 1, Hl - 1);
    const float* tb = tarr[li] + (size_t)((b << 6) + o) * Hl * Hl;
    float v00 = tb[y0*Hl + x0], v01 = tb[y0*Hl + x1];
    float v10 = tb[y1*Hl + x0], v11 = tb[y1*Hl + x1];
    acc += (1.f-fy)*((1.f-fx)*v00 + fx*v01) + fy*((1.f-fx)*v10 + fx*v11);
  }
  out[i] = acc;
}

extern "C" void kernel_launch(void* const* d_in, const int* in_sizes, int n_in,
                              void* d_out, int out_size, void* d_ws, size_t ws_size,
                              hipStream_t stream){
  (void)in_sizes; (void)n_in; (void)out_size; (void)ws_size;
  const float* x      = (const float*)d_in[0];
  const float* off_w  = (const float*)d_in[1];
  const float* off_b  = (const float*)d_in[2];
  const float* dc_w   = (const float*)d_in[3];
  const float* dc_b   = (const float*)d_in[4];
  const float* se_w1  = (const float*)d_in[5];
  const float* se_b1  = (const float*)d_in[6];
  const float* se_w2  = (const float*)d_in[7];
  const float* se_b2  = (const float*)d_in[8];
  const float* fuse_w = (const float*)d_in[9];
  const float* fuse_b = (const float*)d_in[10];
  float* out = (float*)d_out;
  float* ws = (float*)d_ws;
  float* cur  = ws + OFF_CUR;
  float* dc   = ws + OFF_DC;
  float* tmp[4] = {ws + OFF_T0, ws + OFF_T1, ws + OFF_T2, ws + OFF_T3};
  float* sums = ws + OFF_SUMS;
  float* g    = ws + OFF_G;
  unsigned* tkt = (unsigned*)(ws + OFF_TKT);

  prep_k<<<(303108 + 255)/256, 256, 0, stream>>>(dc_w, off_w, fuse_w, ws);
  cvt_k<<<1024, 256, 0, stream>>>(x, cur);

  // L0
  deform_k<128,0><<<4096, 256, 0, stream>>>(cur, ws, off_b, dc_b, se_w1, se_b1, se_w2, se_b2, dc, sums, g, tkt);
  fuse_gd_k<128,0><<<1024, 256, 0, stream>>>(dc, g, ws, tmp[0], cur);
  // L1
  deform_k<64,1><<<1024, 256, 0, stream>>>(cur, ws, off_b, dc_b, se_w1, se_b1, se_w2, se_b2, dc, sums, g, tkt);
  fuse_gd_k<64,1><<<256, 256, 0, stream>>>(dc, g, ws, tmp[1], cur);
  // L2
  deform_k<32,2><<<256, 256, 0, stream>>>(cur, ws, off_b, dc_b, se_w1, se_b1, se_w2, se_b2, dc, sums, g, tkt);
  fuse_gd_k<32,2><<<64, 256, 0, stream>>>(dc, g, ws, tmp[2], cur);
  // L3
  deform_k<16,3><<<64, 256, 0, stream>>>(cur, ws, off_b, dc_b, se_w1, se_b1, se_w2, se_b2, dc, sums, g, tkt);
  fuse_gd_k<16,3><<<16, 256, 0, stream>>>(dc, g, ws, tmp[3], nullptr);

  final_k<<<16384, 256, 0, stream>>>(ws, fuse_b, out);
}

// Round 6
// 282.412 us; speedup vs baseline: 1.3944x; 1.3944x over previous
//
#include <hip/hip_runtime.h>
#include <math.h>

// All reference tensors are float32 -> inputs are const float*, output float*.

constexpr int Bn = 4;          // batch

typedef __attribute__((ext_vector_type(8))) short short8;   // 8 bf16 (4 VGPRs)
typedef __attribute__((ext_vector_type(4))) float f32x4;    // MFMA 16x16 acc

static __device__ __forceinline__ short f2b(float f){
  union { float f; unsigned u; } v; v.f = f;
  unsigned r = v.u + 0x7fffu + ((v.u >> 16) & 1u);   // RNE
  return (short)(r >> 16);
}

// ---- workspace layout (float offsets; all multiples of 4 -> 16B aligned) ----
constexpr size_t OFF_CUR   = 0;                         // 4*16384*64 f32 NHWC (per level, reused)
constexpr size_t OFF_DC    = OFF_CUR  + 4194304;        // 4*16384*64 f32 NHWC
constexpr size_t OFF_T0    = OFF_DC   + 4194304;        // fuse outputs, CHW [b][o][p]
constexpr size_t OFF_T1    = OFF_T0   + 4194304;
constexpr size_t OFF_T2    = OFF_T1   + 1048576;
constexpr size_t OFF_T3    = OFF_T2   + 262144;
constexpr size_t OFF_WSUMT = OFF_T3   + 65536;          // bf16 [4][64][64]   kdim=c
constexpr size_t OFF_DCWT  = OFF_WSUMT + 8192;          // bf16 [4][64][576]  kdim=c*9+k
constexpr size_t OFF_OWT   = OFF_DCWT  + 73728;         // bf16 [4][32][576]  kdim=c*9+k
constexpr size_t OFF_SUMS  = OFF_OWT   + 36864;         // f32 [4][64 slots][256]
constexpr size_t OFF_G     = OFF_SUMS  + 65536;         // f32 [4][4][64]

// ---- prep: weights -> bf16 (N-major, kdim=c*9+k), cumulative fuse, zero SE sums ----
__global__ void prep_k(const float* __restrict__ dc_w, const float* __restrict__ off_w,
                       const float* __restrict__ fuse_w, float* __restrict__ ws){
  int i = blockIdx.x * 256 + threadIdx.x;
  short* dcwT  = (short*)(ws + OFF_DCWT);
  short* owT   = (short*)(ws + OFF_OWT);
  short* wsumT = (short*)(ws + OFF_WSUMT);
  if (i < 147456){
    dcwT[i] = f2b(dc_w[i]);                       // [l][o][c*9+kt] == flat order
  } else if (i < 147456 + 73728){
    int t = i - 147456;
    int l = t / 18432, r = t % 18432, m = r / 576, k = r % 576;
    owT[t] = (m < 18) ? f2b(off_w[(l*18 + m)*576 + k]) : (short)0;
  } else if (i < 147456 + 73728 + 16384){
    int t = i - (147456 + 73728);
    int l = t / 4096, r = t % 4096, o = r / 64, c = r % 64;
    float s = 0.f;
    for (int jl = 0; jl <= l; jl++) s += fuse_w[o*256 + jl*64 + c];
    wsumT[t] = f2b(s);
  } else if (i < 147456 + 73728 + 16384 + 65536){
    ws[OFF_SUMS + (i - (147456 + 73728 + 16384))] = 0.f;
  }
}

// ---- convert x: NCHW -> NHWC via LDS-tiled transpose (coalesced both sides) ----
__global__ __launch_bounds__(256) void cvt_k(const float* __restrict__ x, float* __restrict__ cur){
  __shared__ float t[64][65];
  int tile = blockIdx.x;                 // 1024 tiles: b(4) x 256 pixel-groups
  int b = tile >> 8, p0 = (tile & 255) << 6;
  int tx = threadIdx.x & 63, ty = threadIdx.x >> 6;
  #pragma unroll
  for (int c = ty; c < 64; c += 4)
    t[c][tx] = x[(((size_t)(b << 6) + c) << 14) + p0 + tx];
  __syncthreads();
  #pragma unroll
  for (int pp = ty; pp < 64; pp += 4)
    cur[(((size_t)(b << 14)) + p0 + pp) * 64 + tx] = t[tx][pp];
}

// ---- fused: offset conv (MFMA) + bilinear sampling + deform GEMM (MFMA) + SE colsum ----
// 4 waves per block, 16 pixels; round-4 structure (wave-uniform taps, lane=channel)
template<int H, int LVL>
__global__ __launch_bounds__(256, 7) void deform_k(
    const float* __restrict__ cur, const float* __restrict__ ws_all,
    const float* __restrict__ off_bias, const float* __restrict__ dc_bias,
    float* __restrict__ dc, float* __restrict__ sums){
  constexpr int W = H, P = H * W;
  __shared__ __align__(16) short valA[16][584];   // bf16, pad 576->584 (16B-aligned rows)
  __shared__ float offs[16][18];
  __shared__ float4 tapW[144];                    // bilinear corner weights
  __shared__ int    tapP[144];                    // packed clamped corners: y0|x0<<7|y1<<14|x1<<21
  const short* owt = (const short*)(ws_all + OFF_OWT) + LVL * 32 * 576;
  const short* dcw = (const short*)(ws_all + OFF_DCWT) + (size_t)LVL * 64 * 576;
  const int tid = threadIdx.x;
  const int wave = tid >> 6, lane = tid & 63;
  const int c0 = lane & 15, quad = lane >> 4, q4 = quad * 4;
  const int pix0 = blockIdx.x * 16;
  const int b = pix0 / P, pb = pix0 % P;
  const float* curb = cur + (size_t)b * P * 64;

  // A: stage zero-padded patches, bf16 (lane = channel; wave's 4 pixels; taps uniform)
  for (int p = wave*4; p < wave*4 + 4; p++){
    int pp = pb + p, h = pp / W, w = pp % W;
    #pragma unroll
    for (int k = 0; k < 9; k++){
      int yy = h + k/3 - 1, xx = w + k%3 - 1;
      bool valid = (yy >= 0) & (yy < H) & (xx >= 0) & (xx < W);
      int idx = valid ? (yy * W + xx) : 0;
      float m = valid ? 1.f : 0.f;
      float v = curb[(size_t)idx * 64 + lane] * m;
      valA[p][lane*9 + k] = f2b(v);
    }
  }
  __syncthreads();

  // B: offset conv via MFMA [16x576]@[576x32]; waves 0/1; split dependent chain
  if (wave < 2){
    f32x4 o0 = {0,0,0,0}, o1 = {0,0,0,0};
    #pragma unroll
    for (int kb = 0; kb < 9; kb++){
      short8 a  = *(const short8*)&valA[c0][kb*32 + quad*8];
      short8 bf = *(const short8*)&owt[(wave*16 + c0)*576 + kb*32 + quad*8];
      o0 = __builtin_amdgcn_mfma_f32_16x16x32_bf16(a, bf, o0, 0, 0, 0);
    }
    #pragma unroll
    for (int kb = 9; kb < 18; kb++){
      short8 a  = *(const short8*)&valA[c0][kb*32 + quad*8];
      short8 bf = *(const short8*)&owt[(wave*16 + c0)*576 + kb*32 + quad*8];
      o1 = __builtin_amdgcn_mfma_f32_16x16x32_bf16(a, bf, o1, 0, 0, 0);
    }
    int comp = wave*16 + c0;
    if (comp < 18){
      float ob = off_bias[LVL*18 + comp];
      #pragma unroll
      for (int r = 0; r < 4; r++) offs[q4 + r][comp] = o0[r] + o1[r] + ob;
    }
  }
  __syncthreads();

  // C0: per-tap bilinear weights + packed clamped corner coords
  if (tid < 144){
    int p = tid / 9, k = tid % 9;
    int pp = pb + p, h = pp / W, w = pp % W;
    float py = (float)(h + k/3 - 1) + offs[p][2*k];
    float px = (float)(w + k%3 - 1) + offs[p][2*k + 1];
    float y0f = floorf(py), x0f = floorf(px);
    float fy = py - y0f, fx = px - x0f;
    int y0 = (int)y0f, x0 = (int)x0f, y1 = y0 + 1, x1 = x0 + 1;
    bool vy0 = (y0 >= 0) & (y0 < H), vy1 = (y1 >= 0) & (y1 < H);
    bool vx0 = (x0 >= 0) & (x0 < W), vx1 = (x1 >= 0) & (x1 < W);
    int y0c = min(max(y0, 0), H-1), y1c = min(max(y1, 0), H-1);
    int x0c = min(max(x0, 0), W-1), x1c = min(max(x1, 0), W-1);
    float gy = 1.f - fy, gx = 1.f - fx;
    tapW[tid] = make_float4((vy0 & vx0) ? gy*gx : 0.f,
                            (vy0 & vx1) ? gy*fx : 0.f,
                            (vy1 & vx0) ? fy*gx : 0.f,
                            (vy1 & vx1) ? fy*fx : 0.f);
    tapP[tid] = y0c | (x0c << 7) | (y1c << 14) | (x1c << 21);
  }
  __syncthreads();

  // C1: sample (lane = channel; wave's 4 pixels; taps uniform); overwrite valA
  for (int p = wave*4; p < wave*4 + 4; p++){
    #pragma unroll
    for (int k = 0; k < 9; k++){
      float4 wv = tapW[p*9 + k];
      int    pc = tapP[p*9 + k];
      int y0c = pc & 127, x0c = (pc >> 7) & 127, y1c = (pc >> 14) & 127, x1c = (pc >> 21) & 127;
      float v = wv.x * curb[(size_t)(y0c*W + x0c)*64 + lane]
              + wv.y * curb[(size_t)(y0c*W + x1c)*64 + lane]
              + wv.z * curb[(size_t)(y1c*W + x0c)*64 + lane]
              + wv.w * curb[(size_t)(y1c*W + x1c)*64 + lane];
      valA[p][lane*9 + k] = f2b(v);
    }
  }
  __syncthreads();

  // D: deform GEMM [16x576]@[576x64]; wave w takes cols 16w..16w+15; split chain
  const int n = wave*16 + c0;
  float bt = dc_bias[LVL*64 + n];
  f32x4 d0 = {bt, bt, bt, bt}, d1 = {0,0,0,0};
  #pragma unroll
  for (int kb = 0; kb < 9; kb++){
    short8 a  = *(const short8*)&valA[c0][kb*32 + quad*8];
    short8 bf = *(const short8*)&dcw[n*576 + kb*32 + quad*8];
    d0 = __builtin_amdgcn_mfma_f32_16x16x32_bf16(a, bf, d0, 0, 0, 0);
  }
  #pragma unroll
  for (int kb = 9; kb < 18; kb++){
    short8 a  = *(const short8*)&valA[c0][kb*32 + quad*8];
    short8 bf = *(const short8*)&dcw[n*576 + kb*32 + quad*8];
    d1 = __builtin_amdgcn_mfma_f32_16x16x32_bf16(a, bf, d1, 0, 0, 0);
  }
  f32x4 acc;
  #pragma unroll
  for (int r = 0; r < 4; r++) acc[r] = d0[r] + d1[r];
  float* dcb = dc + (size_t)pix0 * 64;
  #pragma unroll
  for (int r = 0; r < 4; r++) dcb[(q4 + r)*64 + n] = acc[r];
  float s = acc[0] + acc[1] + acc[2] + acc[3];
  s += __shfl_xor(s, 16);
  s += __shfl_xor(s, 32);
  if (quad == 0) atomicAdd(&sums[(LVL*64 + (blockIdx.x & 63))*256 + (b << 6) + n], s);
}

// ---- SE: reduce slotted sums -> mean -> fc-relu-fc-sigmoid -> gates ----
__global__ void se_k(const float* __restrict__ sums, const float* __restrict__ w1p,
                     const float* __restrict__ b1p, const float* __restrict__ w2p,
                     const float* __restrict__ b2p, float* __restrict__ g, int l, int P){
  __shared__ float m_s[256];
  __shared__ float h_s[16];
  int t = threadIdx.x;
  float s = 0.f;
  for (int slot = 0; slot < 64; slot++) s += sums[(l*64 + slot)*256 + t];
  m_s[t] = s / (float)P;
  __syncthreads();
  if (t < 16){
    int b = t >> 2, r = t & 3;
    float a = b1p[l*4 + r];
    for (int c = 0; c < 64; c++) a += m_s[b*64 + c] * w1p[(l*4 + r)*64 + c];
    h_s[t] = fmaxf(a, 0.f);
  }
  __syncthreads();
  int b = t >> 6, c = t & 63;
  float a = b2p[l*64 + c];
  for (int r = 0; r < 4; r++) a += h_s[b*4 + r] * w2p[(l*64 + c)*4 + r];
  g[l*256 + t] = 1.f / (1.f + expf(-a));
}

// ---- fuse + gate + downsample: (dc*g) @ Wsum_l -> tmp_l (CHW); 2x2 avg pool -> cur_{l+1} ----
template<int W, int LVL>
__global__ __launch_bounds__(256) void fuse_gd_k(
    const float* __restrict__ dcv, const float* __restrict__ g,
    const float* __restrict__ ws_all, float* __restrict__ tmp, float* __restrict__ curn){
  constexpr int P = W * W;
  constexpr bool POOL = (LVL < 3);
  __shared__ __align__(16) float fS[64][68];      // gated fp32 values, pad 64->68
  const short* wsl = (const short*)(ws_all + OFF_WSUMT) + LVL * 4096;
  const int tid = threadIdx.x, wave = tid >> 6, lane = tid & 63;
  const int c0 = lane & 15, quad = lane >> 4, q4 = quad * 4;
  int b, rp = 0, cs = 0;
  if (POOL){
    constexpr int tilesPerB = P / 64, tilesPerRow = W / 32;
    b = blockIdx.x / tilesPerB;
    int r = blockIdx.x % tilesPerB;
    rp = r / tilesPerRow; cs = r % tilesPerRow;
  } else {
    b = (blockIdx.x * 64) / P;
  }
  // stage gated fp32 values
  float4 g4 = *(const float4*)&g[LVL*256 + (b << 6) + c0*4];
  #pragma unroll
  for (int i = 0; i < 4; i++){
    int lp = wave*16 + (lane >> 4) + i*4;
    size_t gpix = POOL ? ((size_t)b*P + (size_t)(2*rp + (lp >> 5))*W + cs*32 + (lp & 31))
                       : ((size_t)blockIdx.x*64 + lp);
    float4 d = *(const float4*)&dcv[gpix*64 + c0*4];
    float4 v = make_float4(d.x*g4.x, d.y*g4.y, d.z*g4.z, d.w*g4.w);
    *(float4*)&fS[lp][c0*4] = v;
  }
  __syncthreads();
  // fuse MFMA [16x64]@[64x64] per wave
  f32x4 acc[4] = {{0,0,0,0},{0,0,0,0},{0,0,0,0},{0,0,0,0}};
  #pragma unroll
  for (int kb = 0; kb < 2; kb++){
    float4 lo = *(const float4*)&fS[wave*16 + c0][kb*32 + quad*8];
    float4 hi = *(const float4*)&fS[wave*16 + c0][kb*32 + quad*8 + 4];
    short8 a = {f2b(lo.x), f2b(lo.y), f2b(lo.z), f2b(lo.w),
                f2b(hi.x), f2b(hi.y), f2b(hi.z), f2b(hi.w)};
    #pragma unroll
    for (int t = 0; t < 4; t++){
      short8 bf = *(const short8*)&wsl[(t*16 + c0)*64 + kb*32 + quad*8];
      acc[t] = __builtin_amdgcn_mfma_f32_16x16x32_bf16(a, bf, acc[t], 0, 0, 0);
    }
  }
  #pragma unroll
  for (int t = 0; t < 4; t++){
    int n = t*16 + c0;
    size_t plane = ((size_t)(b << 6) + n) * P;
    size_t pix = POOL ? ((size_t)(2*rp + (wave >> 1))*W + cs*32 + (wave & 1)*16 + q4)
                      : ((size_t)(blockIdx.x*64) - (size_t)b*P + wave*16 + q4);
    *(f32x4*)&tmp[plane + pix] = acc[t];
  }
  // 2x2 avg pool of gated values -> next level input (NHWC)
  if constexpr (POOL){
    int j = tid >> 4, uu = tid & 15;
    float4 p0 = *(const float4*)&fS[2*j][uu*4];
    float4 p1 = *(const float4*)&fS[2*j + 1][uu*4];
    float4 p2 = *(const float4*)&fS[32 + 2*j][uu*4];
    float4 p3 = *(const float4*)&fS[33 + 2*j][uu*4];
    float4 av = make_float4(0.25f*(p0.x + p1.x + p2.x + p3.x),
                            0.25f*(p0.y + p1.y + p2.y + p3.y),
                            0.25f*(p0.z + p1.z + p2.z + p3.z),
                            0.25f*(p0.w + p1.w + p2.w + p3.w));
    *(float4*)&curn[((size_t)b*(P/4) + (size_t)rp*(W/2) + cs*16 + j)*64 + uu*4] = av;
  }
}

// ---- final: 4x bilinear upsample (CHW planes) + sum + fuse bias -> f32 NCHW ----
__global__ void final_k(const float* __restrict__ ws_all, const float* __restrict__ fuse_bias,
                        float* __restrict__ out){
  int i = blockIdx.x * 256 + threadIdx.x;
  int w = i & 127, h = (i >> 7) & 127, o = (i >> 14) & 63, b = i >> 20;
  float acc = fuse_bias[o] + ws_all[OFF_T0 + (((size_t)(b << 6) + o) << 14) + (h << 7) + w];
  const float* tarr[3] = {ws_all + OFF_T1, ws_all + OFF_T2, ws_all + OFF_T3};
  #pragma unroll
  for (int li = 0; li < 3; li++){
    int l = li + 1, Hl = 128 >> l;
    float scale = 1.0f / (float)(1 << l);
    float sy = fminf(fmaxf((h + 0.5f)*scale - 0.5f, 0.f), (float)(Hl - 1));
    float sx = fminf(fmaxf((w + 0.5f)*scale - 0.5f, 0.f), (float)(Hl - 1));
    int y0 = (int)sy, x0 = (int)sx;
    float fy = sy - y0, fx = sx - x0;
    int y1 = min(y0 + 1, Hl - 1), x1 = min(x0 + 1, Hl - 1);
    const float* tb = tarr[li] + (size_t)((b << 6) + o) * Hl * Hl;
    float v00 = tb[y0*Hl + x0], v01 = tb[y0*Hl + x1];
    float v10 = tb[y1*Hl + x0], v11 = tb[y1*Hl + x1];
    acc += (1.f-fy)*((1.f-fx)*v00 + fx*v01) + fy*((1.f-fx)*v10 + fx*v11);
  }
  out[i] = acc;
}

extern "C" void kernel_launch(void* const* d_in, const int* in_sizes, int n_in,
                              void* d_out, int out_size, void* d_ws, size_t ws_size,
                              hipStream_t stream){
  (void)in_sizes; (void)n_in; (void)out_size; (void)ws_size;
  const float* x      = (const float*)d_in[0];
  const float* off_w  = (const float*)d_in[1];
  const float* off_b  = (const float*)d_in[2];
  const float* dc_w   = (const float*)d_in[3];
  const float* dc_b   = (const float*)d_in[4];
  const float* se_w1  = (const float*)d_in[5];
  const float* se_b1  = (const float*)d_in[6];
  const float* se_w2  = (const float*)d_in[7];
  const float* se_b2  = (const float*)d_in[8];
  const float* fuse_w = (const float*)d_in[9];
  const float* fuse_b = (const float*)d_in[10];
  float* out = (float*)d_out;
  float* ws = (float*)d_ws;
  float* cur  = ws + OFF_CUR;
  float* dc   = ws + OFF_DC;
  float* tmp[4] = {ws + OFF_T0, ws + OFF_T1, ws + OFF_T2, ws + OFF_T3};
  float* sums = ws + OFF_SUMS;
  float* g    = ws + OFF_G;

  prep_k<<<(303104 + 255)/256, 256, 0, stream>>>(dc_w, off_w, fuse_w, ws);
  cvt_k<<<1024, 256, 0, stream>>>(x, cur);

  // L0
  deform_k<128,0><<<4096, 256, 0, stream>>>(cur, ws, off_b, dc_b, dc, sums);
  se_k<<<1, 256, 0, stream>>>(sums, se_w1, se_b1, se_w2, se_b2, g, 0, 16384);
  fuse_gd_k<128,0><<<1024, 256, 0, stream>>>(dc, g, ws, tmp[0], cur);
  // L1
  deform_k<64,1><<<1024, 256, 0, stream>>>(cur, ws, off_b, dc_b, dc, sums);
  se_k<<<1, 256, 0, stream>>>(sums, se_w1, se_b1, se_w2, se_b2, g, 1, 4096);
  fuse_gd_k<64,1><<<256, 256, 0, stream>>>(dc, g, ws, tmp[1], cur);
  // L2
  deform_k<32,2><<<256, 256, 0, stream>>>(cur, ws, off_b, dc_b, dc, sums);
  se_k<<<1, 256, 0, stream>>>(sums, se_w1, se_b1, se_w2, se_b2, g, 2, 1024);
  fuse_gd_k<32,2><<<64, 256, 0, stream>>>(dc, g, ws, tmp[2], cur);
  // L3
  deform_k<16,3><<<64, 256, 0, stream>>>(cur, ws, off_b, dc_b, dc, sums);
  se_k<<<1, 256, 0, stream>>>(sums, se_w1, se_b1, se_w2, se_b2, g, 3, 256);
  fuse_gd_k<16,3><<<16, 256, 0, stream>>>(dc, g, ws, tmp[3], nullptr);

  final_k<<<16384, 256, 0, stream>>>(ws, fuse_b, out);
}

// Round 7
// 273.310 us; speedup vs baseline: 1.4408x; 1.0333x over previous
//
#include <hip/hip_runtime.h>
#include <hip/hip_bf16.h>
#include <math.h>

// All reference tensors are float32 -> inputs are const float*, output float*.

constexpr int Bn = 4;          // batch

typedef __attribute__((ext_vector_type(8))) short short8;   // 8 bf16 (4 VGPRs)
typedef __attribute__((ext_vector_type(4))) float f32x4;    // MFMA 16x16 acc
typedef __attribute__((ext_vector_type(4))) unsigned uint4v;

static __device__ __forceinline__ short f2b(float f){
  union { float f; unsigned u; } v; v.f = f;
  unsigned r = v.u + 0x7fffu + ((v.u >> 16) & 1u);   // RNE
  return (short)(r >> 16);
}
// packed f32x2 -> bf16x2 (v_cvt_pk_bf16_f32 on gfx950); low short = x
static __device__ __forceinline__ unsigned f2b2(float x, float y){
  union { __hip_bfloat162 h; unsigned u; } cv;
  cv.h = __float22bfloat162_rn(make_float2(x, y));
  return cv.u;
}

// ---- workspace layout (float offsets; all multiples of 4 -> 16B aligned) ----
constexpr size_t OFF_CUR   = 0;                         // 4*16384*64 f32 NHWC (per level, reused)
constexpr size_t OFF_DC    = OFF_CUR  + 4194304;        // 4*16384*64 f32 NHWC
constexpr size_t OFF_T0    = OFF_DC   + 4194304;        // fuse outputs, CHW [b][o][p]
constexpr size_t OFF_T1    = OFF_T0   + 4194304;
constexpr size_t OFF_T2    = OFF_T1   + 1048576;
constexpr size_t OFF_T3    = OFF_T2   + 262144;
constexpr size_t OFF_WSUMT = OFF_T3   + 65536;          // bf16 [4][64][64]   kdim=c
constexpr size_t OFF_DCWT  = OFF_WSUMT + 8192;          // bf16 [4][64][576]  kdim=k*64+c
constexpr size_t OFF_OWT   = OFF_DCWT  + 73728;         // bf16 [4][32][576]  kdim=k*64+c
constexpr size_t OFF_SUMS  = OFF_OWT   + 36864;         // f32 [4][16 slots][256] (64-slot region kept)
// total fits well inside ws

// ---- prep: weights -> bf16 (N-major, kdim=k*64+c), cumulative fuse, zero SE sums ----
__global__ void prep_k(const float* __restrict__ dc_w, const float* __restrict__ off_w,
                       const float* __restrict__ fuse_w, float* __restrict__ ws){
  int i = blockIdx.x * 256 + threadIdx.x;
  short* dcwT  = (short*)(ws + OFF_DCWT);
  short* owT   = (short*)(ws + OFF_OWT);
  short* wsumT = (short*)(ws + OFF_WSUMT);
  if (i < 147456){
    int oc = i / 576, r = i % 576, k = r >> 6, c = r & 63;      // oc = l*64+o
    dcwT[i] = f2b(dc_w[(oc*64 + c)*9 + k]);
  } else if (i < 147456 + 73728){
    int t = i - 147456;
    int lm = t / 576, l = lm >> 5, m = lm & 31, r = t % 576, k = r >> 6, c = r & 63;
    owT[t] = (m < 18) ? f2b(off_w[((l*18 + m)*64 + c)*9 + k]) : (short)0;
  } else if (i < 147456 + 73728 + 16384){
    int t = i - (147456 + 73728);
    int l = t / 4096, r = t % 4096, o = r / 64, c = r % 64;
    float s = 0.f;
    for (int jl = 0; jl <= l; jl++) s += fuse_w[o*256 + jl*64 + c];
    wsumT[t] = f2b(s);
  } else if (i < 147456 + 73728 + 16384 + 65536){
    ws[OFF_SUMS + (i - (147456 + 73728 + 16384))] = 0.f;
  }
}

// ---- convert x: NCHW -> NHWC via LDS-tiled transpose (coalesced both sides) ----
__global__ __launch_bounds__(256) void cvt_k(const float* __restrict__ x, float* __restrict__ cur){
  __shared__ float t[64][65];
  int tile = blockIdx.x;                 // 1024 tiles: b(4) x 256 pixel-groups
  int b = tile >> 8, p0 = (tile & 255) << 6;
  int tx = threadIdx.x & 63, ty = threadIdx.x >> 6;
  #pragma unroll
  for (int c = ty; c < 64; c += 4)
    t[c][tx] = x[(((size_t)(b << 6) + c) << 14) + p0 + tx];
  __syncthreads();
  #pragma unroll
  for (int pp = ty; pp < 64; pp += 4)
    cur[(((size_t)(b << 14)) + p0 + pp) * 64 + tx] = t[tx][pp];
}

// ---- fused: offset conv (MFMA, 4 waves) + bilinear sampling + deform GEMM + SE colsum ----
// 4 waves, 16 pixels/block (one row segment). kdim = tap*64 + ch. Staging/sampling:
// half-wave per tap, 2 channels (float2) per lane, packed bf16 converts, b32 LDS writes.
template<int H, int LVL>
__global__ __launch_bounds__(256, 6) void deform_k(
    const float* __restrict__ cur, const float* __restrict__ ws_all,
    const float* __restrict__ off_bias, const float* __restrict__ dc_bias,
    float* __restrict__ dc, float* __restrict__ sums){
  constexpr int W = H, P = H * W;
  constexpr int PITCHB = 584 * 2;                 // valA row pitch in bytes (pad 576->584)
  __shared__ __align__(16) short valA[16][584];   // bf16 [pixel][kdim]
  __shared__ float offsP[2][16][18];              // offset-conv K-partials
  __shared__ float4 tapW[144];                    // bilinear corner weights
  __shared__ int4   tapI[144];                    // corner byte offsets (idx*256)
  const short* owt = (const short*)(ws_all + OFF_OWT) + LVL * 32 * 576;
  const short* dcw = (const short*)(ws_all + OFF_DCWT) + (size_t)LVL * 64 * 576;
  const int tid = threadIdx.x;
  const int wave = tid >> 6, lane = tid & 63;
  const int c0 = lane & 15, quad = lane >> 4, q4 = quad * 4;
  const int half = lane >> 5, cc = lane & 31;     // staging role
  const int pix0 = blockIdx.x * 16;
  const int b = pix0 / P, pb = pix0 % P;
  const int hrow = pb / W, wcol = pb % W;         // 16 pixels all in one row
  const float* curb = cur + (size_t)b * P * 64;
  const char* curc = (const char*)curb + cc * 8;
  char* valc = (char*)valA + wave * (4 * PITCHB);

  // A: stage zero-padded 3x3 patches, bf16; 2 taps/iter (half-wave each), float2/lane
  #pragma unroll
  for (int i = 0; i < 18; i++){
    const int t0 = 2*i, t1 = t0 + 1;
    const int p0 = t0/9, k0 = t0%9, p1 = t1/9, k1 = t1%9;
    int yy0 = hrow + k0/3 - 1, xx0 = wcol + wave*4 + p0 + k0%3 - 1;
    int yy1 = hrow + k1/3 - 1, xx1 = wcol + wave*4 + p1 + k1%3 - 1;
    bool v0 = ((unsigned)yy0 < (unsigned)H) & ((unsigned)xx0 < (unsigned)W);
    bool v1 = ((unsigned)yy1 < (unsigned)H) & ((unsigned)xx1 < (unsigned)W);
    int  i0 = v0 ? (yy0*W + xx0) : 0,  i1 = v1 ? (yy1*W + xx1) : 0;
    float m0 = v0 ? 1.f : 0.f,         m1 = v1 ? 1.f : 0.f;
    int   idx = half ? i1 : i0;
    float m   = half ? m1 : m0;
    float2 v = *(const float2*)(curc + (size_t)idx * 256);
    unsigned pk = f2b2(v.x * m, v.y * m);
    const int ob0 = p0*PITCHB + k0*128, ob1 = p1*PITCHB + k1*128;
    *(unsigned*)(valc + (half ? ob1 : ob0) + cc*4) = pk;
  }
  __syncthreads();

  // B: offset conv [16x576]@[576x32] split over 4 waves (2 col-halves x 2 K-halves)
  {
    const int colw = wave & 1, kh = wave >> 1;
    f32x4 oacc = {0,0,0,0};
    #pragma unroll
    for (int kb = 0; kb < 9; kb++){
      int kk = kh*9 + kb;
      short8 a  = *(const short8*)&valA[c0][kk*32 + quad*8];
      short8 bf = *(const short8*)&owt[(colw*16 + c0)*576 + kk*32 + quad*8];
      oacc = __builtin_amdgcn_mfma_f32_16x16x32_bf16(a, bf, oacc, 0, 0, 0);
    }
    int comp = colw*16 + c0;
    if (comp < 18){
      #pragma unroll
      for (int r = 0; r < 4; r++) offsP[kh][q4 + r][comp] = oacc[r];
    }
  }
  __syncthreads();

  // C0: per-tap bilinear weights + corner byte offsets
  if (tid < 144){
    int p = tid / 9, k = tid % 9;
    int h = hrow, w = wcol + p;
    float oy = offsP[0][p][2*k]     + offsP[1][p][2*k]     + off_bias[LVL*18 + 2*k];
    float ox = offsP[0][p][2*k + 1] + offsP[1][p][2*k + 1] + off_bias[LVL*18 + 2*k + 1];
    float py = (float)(h + k/3 - 1) + oy;
    float px = (float)(w + k%3 - 1) + ox;
    float y0f = floorf(py), x0f = floorf(px);
    float fy = py - y0f, fx = px - x0f;
    int y0 = (int)y0f, x0 = (int)x0f, y1 = y0 + 1, x1 = x0 + 1;
    bool vy0 = (y0 >= 0) & (y0 < H), vy1 = (y1 >= 0) & (y1 < H);
    bool vx0 = (x0 >= 0) & (x0 < W), vx1 = (x1 >= 0) & (x1 < W);
    int y0c = min(max(y0, 0), H-1), y1c = min(max(y1, 0), H-1);
    int x0c = min(max(x0, 0), W-1), x1c = min(max(x1, 0), W-1);
    float gy = 1.f - fy, gx = 1.f - fx;
    tapW[tid] = make_float4((vy0 & vx0) ? gy*gx : 0.f,
                            (vy0 & vx1) ? gy*fx : 0.f,
                            (vy1 & vx0) ? fy*gx : 0.f,
                            (vy1 & vx1) ? fy*fx : 0.f);
    tapI[tid] = make_int4((y0c*W + x0c) << 8, (y0c*W + x1c) << 8,
                          (y1c*W + x0c) << 8, (y1c*W + x1c) << 8);
  }
  __syncthreads();

  // C1: sample; 2 taps/iter (half-wave each), float2/lane; overwrite valA
  #pragma unroll
  for (int i = 0; i < 18; i++){
    int T = wave*36 + 2*i + half;
    float4 wv = tapW[T];
    int4   ti = tapI[T];
    float2 a0 = *(const float2*)(curc + ti.x);
    float2 a1 = *(const float2*)(curc + ti.y);
    float2 a2 = *(const float2*)(curc + ti.z);
    float2 a3 = *(const float2*)(curc + ti.w);
    float vx = wv.x*a0.x + wv.y*a1.x + wv.z*a2.x + wv.w*a3.x;
    float vy = wv.x*a0.y + wv.y*a1.y + wv.z*a2.y + wv.w*a3.y;
    unsigned pk = f2b2(vx, vy);
    const int t0 = 2*i, t1 = t0 + 1;
    const int ob0 = (t0/9)*PITCHB + (t0%9)*128, ob1 = (t1/9)*PITCHB + (t1%9)*128;
    *(unsigned*)(valc + (half ? ob1 : ob0) + cc*4) = pk;
  }
  __syncthreads();

  // D: deform GEMM [16x576]@[576x64]; wave w takes cols 16w..16w+15; split chain
  const int n = wave*16 + c0;
  float bt = dc_bias[LVL*64 + n];
  f32x4 d0 = {bt, bt, bt, bt}, d1 = {0,0,0,0};
  #pragma unroll
  for (int kb = 0; kb < 9; kb++){
    short8 a  = *(const short8*)&valA[c0][kb*32 + quad*8];
    short8 bf = *(const short8*)&dcw[n*576 + kb*32 + quad*8];
    d0 = __builtin_amdgcn_mfma_f32_16x16x32_bf16(a, bf, d0, 0, 0, 0);
  }
  #pragma unroll
  for (int kb = 9; kb < 18; kb++){
    short8 a  = *(const short8*)&valA[c0][kb*32 + quad*8];
    short8 bf = *(const short8*)&dcw[n*576 + kb*32 + quad*8];
    d1 = __builtin_amdgcn_mfma_f32_16x16x32_bf16(a, bf, d1, 0, 0, 0);
  }
  f32x4 acc;
  #pragma unroll
  for (int r = 0; r < 4; r++) acc[r] = d0[r] + d1[r];
  float* dcb = dc + (size_t)pix0 * 64;
  #pragma unroll
  for (int r = 0; r < 4; r++) dcb[(q4 + r)*64 + n] = acc[r];
  float s = acc[0] + acc[1] + acc[2] + acc[3];
  s += __shfl_xor(s, 16);
  s += __shfl_xor(s, 32);
  if (quad == 0) atomicAdd(&sums[(LVL*16 + (blockIdx.x & 15))*256 + (b << 6) + n], s);
}

// ---- fuse + SE gates + gate + downsample: gates from sums (per block), then
//      (dc*g) @ Wsum_l -> tmp_l (CHW); 2x2 avg pool of gated vals -> cur_{l+1} ----
template<int W, int LVL>
__global__ __launch_bounds__(256) void fuse_gd_k(
    const float* __restrict__ dcv, const float* __restrict__ sums,
    const float* __restrict__ se_w1, const float* __restrict__ se_b1,
    const float* __restrict__ se_w2, const float* __restrict__ se_b2,
    const float* __restrict__ ws_all, float* __restrict__ tmp, float* __restrict__ curn){
  constexpr int P = W * W;
  constexpr bool POOL = (LVL < 3);
  constexpr float invP = 1.f / (float)P;
  __shared__ __align__(16) float fS[64][68];      // gated fp32 values, pad 64->68
  __shared__ __align__(16) float gsh[64];
  const short* wsl = (const short*)(ws_all + OFF_WSUMT) + LVL * 4096;
  const int tid = threadIdx.x, wave = tid >> 6, lane = tid & 63;
  const int c0 = lane & 15, quad = lane >> 4, q4 = quad * 4;
  int b, rp = 0, cs = 0;
  if (POOL){
    constexpr int tilesPerB = P / 64, tilesPerRow = W / 32;
    b = blockIdx.x / tilesPerB;
    int r = blockIdx.x % tilesPerB;
    rp = r / tilesPerRow; cs = r % tilesPerRow;
  } else {
    b = (blockIdx.x * 64) / P;
  }

  // SE gates (redundant per block): slot partials -> mean -> fc-relu-fc-sigmoid
  {
    int sg = tid >> 6, c = tid & 63;
    float part = 0.f;
    #pragma unroll
    for (int s = 0; s < 4; s++) part += sums[(LVL*16 + sg*4 + s)*256 + (b << 6) + c];
    fS[sg][c] = part;
    __syncthreads();
    if (tid < 64){
      int r = tid & 3, j = tid >> 2;
      float hp = 0.f;
      #pragma unroll
      for (int q = 0; q < 4; q++){
        int cq = j*4 + q;
        float m = (fS[0][cq] + fS[1][cq] + fS[2][cq] + fS[3][cq]) * invP;
        hp += m * se_w1[(LVL*4 + r)*64 + cq];
      }
      hp += __shfl_xor(hp, 4);  hp += __shfl_xor(hp, 8);
      hp += __shfl_xor(hp, 16); hp += __shfl_xor(hp, 32);
      float hr = fmaxf(hp + se_b1[LVL*4 + r], 0.f);
      float a = se_b2[LVL*64 + tid];
      #pragma unroll
      for (int r2 = 0; r2 < 4; r2++)
        a += __shfl(hr, r2) * se_w2[(LVL*64 + tid)*4 + r2];
      gsh[tid] = 1.f / (1.f + expf(-a));
    }
    __syncthreads();
  }

  // stage gated fp32 values
  float4 g4 = *(const float4*)&gsh[c0*4];
  #pragma unroll
  for (int i = 0; i < 4; i++){
    int lp = wave*16 + (lane >> 4) + i*4;
    size_t gpix = POOL ? ((size_t)b*P + (size_t)(2*rp + (lp >> 5))*W + cs*32 + (lp & 31))
                       : ((size_t)blockIdx.x*64 + lp);
    float4 d = *(const float4*)&dcv[gpix*64 + c0*4];
    float4 v = make_float4(d.x*g4.x, d.y*g4.y, d.z*g4.z, d.w*g4.w);
    *(float4*)&fS[lp][c0*4] = v;
  }
  __syncthreads();
  // fuse MFMA [16x64]@[64x64] per wave
  f32x4 acc[4] = {{0,0,0,0},{0,0,0,0},{0,0,0,0},{0,0,0,0}};
  #pragma unroll
  for (int kb = 0; kb < 2; kb++){
    float4 lo = *(const float4*)&fS[wave*16 + c0][kb*32 + quad*8];
    float4 hi = *(const float4*)&fS[wave*16 + c0][kb*32 + quad*8 + 4];
    uint4v ua = {f2b2(lo.x, lo.y), f2b2(lo.z, lo.w), f2b2(hi.x, hi.y), f2b2(hi.z, hi.w)};
    short8 a = __builtin_bit_cast(short8, ua);
    #pragma unroll
    for (int t = 0; t < 4; t++){
      short8 bf = *(const short8*)&wsl[(t*16 + c0)*64 + kb*32 + quad*8];
      acc[t] = __builtin_amdgcn_mfma_f32_16x16x32_bf16(a, bf, acc[t], 0, 0, 0);
    }
  }
  #pragma unroll
  for (int t = 0; t < 4; t++){
    int n = t*16 + c0;
    size_t plane = ((size_t)(b << 6) + n) * P;
    size_t pix = POOL ? ((size_t)(2*rp + (wave >> 1))*W + cs*32 + (wave & 1)*16 + q4)
                      : ((size_t)(blockIdx.x*64) - (size_t)b*P + wave*16 + q4);
    *(f32x4*)&tmp[plane + pix] = acc[t];
  }
  // 2x2 avg pool of gated values -> next level input (NHWC)
  if constexpr (POOL){
    int j = tid >> 4, uu = tid & 15;
    float4 p0 = *(const float4*)&fS[2*j][uu*4];
    float4 p1 = *(const float4*)&fS[2*j + 1][uu*4];
    float4 p2 = *(const float4*)&fS[32 + 2*j][uu*4];
    float4 p3 = *(const float4*)&fS[33 + 2*j][uu*4];
    float4 av = make_float4(0.25f*(p0.x + p1.x + p2.x + p3.x),
                            0.25f*(p0.y + p1.y + p2.y + p3.y),
                            0.25f*(p0.z + p1.z + p2.z + p3.z),
                            0.25f*(p0.w + p1.w + p2.w + p3.w));
    *(float4*)&curn[((size_t)b*(P/4) + (size_t)rp*(W/2) + cs*16 + j)*64 + uu*4] = av;
  }
}

// ---- final: 4x bilinear upsample (CHW planes) + sum + fuse bias -> f32 NCHW ----
__global__ void final_k(const float* __restrict__ ws_all, const float* __restrict__ fuse_bias,
                        float* __restrict__ out){
  int i = blockIdx.x * 256 + threadIdx.x;
  int w = i & 127, h = (i >> 7) & 127, o = (i >> 14) & 63, b = i >> 20;
  float acc = fuse_bias[o] + ws_all[OFF_T0 + (((size_t)(b << 6) + o) << 14) + (h << 7) + w];
  const float* tarr[3] = {ws_all + OFF_T1, ws_all + OFF_T2, ws_all + OFF_T3};
  #pragma unroll
  for (int li = 0; li < 3; li++){
    int l = li + 1, Hl = 128 >> l;
    float scale = 1.0f / (float)(1 << l);
    float sy = fminf(fmaxf((h + 0.5f)*scale - 0.5f, 0.f), (float)(Hl - 1));
    float sx = fminf(fmaxf((w + 0.5f)*scale - 0.5f, 0.f), (float)(Hl - 1));
    int y0 = (int)sy, x0 = (int)sx;
    float fy = sy - y0, fx = sx - x0;
    int y1 = min(y0 + 1, Hl - 1), x1 = min(x0 + 1, Hl - 1);
    const float* tb = tarr[li] + (size_t)((b << 6) + o) * Hl * Hl;
    float v00 = tb[y0*Hl + x0], v01 = tb[y0*Hl + x1];
    float v10 = tb[y1*Hl + x0], v11 = tb[y1*Hl + x1];
    acc += (1.f-fy)*((1.f-fx)*v00 + fx*v01) + fy*((1.f-fx)*v10 + fx*v11);
  }
  out[i] = acc;
}

extern "C" void kernel_launch(void* const* d_in, const int* in_sizes, int n_in,
                              void* d_out, int out_size, void* d_ws, size_t ws_size,
                              hipStream_t stream){
  (void)in_sizes; (void)n_in; (void)out_size; (void)ws_size;
  const float* x      = (const float*)d_in[0];
  const float* off_w  = (const float*)d_in[1];
  const float* off_b  = (const float*)d_in[2];
  const float* dc_w   = (const float*)d_in[3];
  const float* dc_b   = (const float*)d_in[4];
  const float* se_w1  = (const float*)d_in[5];
  const float* se_b1  = (const float*)d_in[6];
  const float* se_w2  = (const float*)d_in[7];
  const float* se_b2  = (const float*)d_in[8];
  const float* fuse_w = (const float*)d_in[9];
  const float* fuse_b = (const float*)d_in[10];
  float* out = (float*)d_out;
  float* ws = (float*)d_ws;
  float* cur  = ws + OFF_CUR;
  float* dc   = ws + OFF_DC;
  float* tmp[4] = {ws + OFF_T0, ws + OFF_T1, ws + OFF_T2, ws + OFF_T3};
  float* sums = ws + OFF_SUMS;

  prep_k<<<(303104 + 255)/256, 256, 0, stream>>>(dc_w, off_w, fuse_w, ws);
  cvt_k<<<1024, 256, 0, stream>>>(x, cur);

  // L0
  deform_k<128,0><<<4096, 256, 0, stream>>>(cur, ws, off_b, dc_b, dc, sums);
  fuse_gd_k<128,0><<<1024, 256, 0, stream>>>(dc, sums, se_w1, se_b1, se_w2, se_b2, ws, tmp[0], cur);
  // L1
  deform_k<64,1><<<1024, 256, 0, stream>>>(cur, ws, off_b, dc_b, dc, sums);
  fuse_gd_k<64,1><<<256, 256, 0, stream>>>(dc, sums, se_w1, se_b1, se_w2, se_b2, ws, tmp[1], cur);
  // L2
  deform_k<32,2><<<256, 256, 0, stream>>>(cur, ws, off_b, dc_b, dc, sums);
  fuse_gd_k<32,2><<<64, 256, 0, stream>>>(dc, sums, se_w1, se_b1, se_w2, se_b2, ws, tmp[2], cur);
  // L3
  deform_k<16,3><<<64, 256, 0, stream>>>(cur, ws, off_b, dc_b, dc, sums);
  fuse_gd_k<16,3><<<16, 256, 0, stream>>>(dc, sums, se_w1, se_b1, se_w2, se_b2, ws, tmp[3], nullptr);

  final_k<<<16384, 256, 0, stream>>>(ws, fuse_b, out);
}

// Round 8
// 270.847 us; speedup vs baseline: 1.4539x; 1.0091x over previous
//
#include <hip/hip_runtime.h>
#include <hip/hip_bf16.h>
#include <math.h>

// All reference tensors are float32 -> inputs are const float*, output float*.

constexpr int Bn = 4;          // batch

typedef __attribute__((ext_vector_type(8))) short short8;   // 8 bf16 (4 VGPRs)
typedef __attribute__((ext_vector_type(4))) float f32x4;    // MFMA 16x16 acc
typedef __attribute__((ext_vector_type(4))) unsigned uint4v;

static __device__ __forceinline__ short f2b(float f){
  union { float f; unsigned u; } v; v.f = f;
  unsigned r = v.u + 0x7fffu + ((v.u >> 16) & 1u);   // RNE
  return (short)(r >> 16);
}
// packed f32x2 -> bf16x2 (v_cvt_pk_bf16_f32 on gfx950); low short = x
static __device__ __forceinline__ unsigned f2b2(float x, float y){
  union { __hip_bfloat162 h; unsigned u; } cv;
  cv.h = __float22bfloat162_rn(make_float2(x, y));
  return cv.u;
}

// ---- workspace layout (float offsets; all multiples of 4 -> 16B aligned) ----
constexpr size_t OFF_CUR   = 0;                         // 4*16384*64 f32 NHWC (per level, reused)
constexpr size_t OFF_DC    = OFF_CUR  + 4194304;        // 4*16384*64 f32 NHWC
constexpr size_t OFF_T0    = OFF_DC   + 4194304;        // fuse outputs, CHW [b][o][p]
constexpr size_t OFF_T1    = OFF_T0   + 4194304;
constexpr size_t OFF_T2    = OFF_T1   + 1048576;
constexpr size_t OFF_T3    = OFF_T2   + 262144;
constexpr size_t OFF_WSUMT = OFF_T3   + 65536;          // bf16 [4][64][64]   kdim=c
constexpr size_t OFF_DCWT  = OFF_WSUMT + 8192;          // bf16 [4][64][576]  kdim=k*64+c
constexpr size_t OFF_OWT   = OFF_DCWT  + 73728;         // bf16 [4][32][576]  kdim=k*64+c
constexpr size_t OFF_SUMS  = OFF_OWT   + 36864;         // f32 [4][16 slots][256]

// ---- prep: weights -> bf16 (N-major, kdim=k*64+c), cumulative fuse, zero SE sums ----
__global__ void prep_k(const float* __restrict__ dc_w, const float* __restrict__ off_w,
                       const float* __restrict__ fuse_w, float* __restrict__ ws){
  int i = blockIdx.x * 256 + threadIdx.x;
  short* dcwT  = (short*)(ws + OFF_DCWT);
  short* owT   = (short*)(ws + OFF_OWT);
  short* wsumT = (short*)(ws + OFF_WSUMT);
  if (i < 147456){
    int oc = i / 576, r = i % 576, k = r >> 6, c = r & 63;      // oc = l*64+o
    dcwT[i] = f2b(dc_w[(oc*64 + c)*9 + k]);
  } else if (i < 147456 + 73728){
    int t = i - 147456;
    int lm = t / 576, l = lm >> 5, m = lm & 31, r = t % 576, k = r >> 6, c = r & 63;
    owT[t] = (m < 18) ? f2b(off_w[((l*18 + m)*64 + c)*9 + k]) : (short)0;
  } else if (i < 147456 + 73728 + 16384){
    int t = i - (147456 + 73728);
    int l = t / 4096, r = t % 4096, o = r / 64, c = r % 64;
    float s = 0.f;
    for (int jl = 0; jl <= l; jl++) s += fuse_w[o*256 + jl*64 + c];
    wsumT[t] = f2b(s);
  } else if (i < 147456 + 73728 + 16384 + 65536){
    ws[OFF_SUMS + (i - (147456 + 73728 + 16384))] = 0.f;
  }
}

// ---- convert x: NCHW -> NHWC via LDS-tiled transpose (coalesced both sides) ----
__global__ __launch_bounds__(256) void cvt_k(const float* __restrict__ x, float* __restrict__ cur){
  __shared__ float t[64][65];
  int tile = blockIdx.x;                 // 1024 tiles: b(4) x 256 pixel-groups
  int b = tile >> 8, p0 = (tile & 255) << 6;
  int tx = threadIdx.x & 63, ty = threadIdx.x >> 6;
  #pragma unroll
  for (int c = ty; c < 64; c += 4)
    t[c][tx] = x[(((size_t)(b << 6) + c) << 14) + p0 + tx];
  __syncthreads();
  #pragma unroll
  for (int pp = ty; pp < 64; pp += 4)
    cur[(((size_t)(b << 14)) + p0 + pp) * 64 + tx] = t[tx][pp];
}

// ---- fused: offset conv (MFMA, 4 waves) + bilinear sampling + deform GEMM + SE colsum ----
// Register-batched loads: A issues all 18 loads before converting; C1 in 3 batches of 6 taps.
template<int H, int LVL>
__global__ __launch_bounds__(256, 5) void deform_k(
    const float* __restrict__ cur, const float* __restrict__ ws_all,
    const float* __restrict__ off_bias, const float* __restrict__ dc_bias,
    float* __restrict__ dc, float* __restrict__ sums){
  constexpr int W = H, P = H * W;
  constexpr int PITCHB = 584 * 2;                 // valA row pitch in bytes (pad 576->584)
  __shared__ __align__(16) short valA[16][584];   // bf16 [pixel][kdim]
  __shared__ float offsP[2][16][18];              // offset-conv K-partials
  __shared__ float4 tapW[144];                    // bilinear corner weights
  __shared__ int4   tapI[144];                    // corner byte offsets (idx*256)
  const short* owt = (const short*)(ws_all + OFF_OWT) + LVL * 32 * 576;
  const short* dcw = (const short*)(ws_all + OFF_DCWT) + (size_t)LVL * 64 * 576;
  const int tid = threadIdx.x;
  const int wave = tid >> 6, lane = tid & 63;
  const int c0 = lane & 15, quad = lane >> 4, q4 = quad * 4;
  const int half = lane >> 5, cc = lane & 31;     // staging role
  const int pix0 = blockIdx.x * 16;
  const int b = pix0 / P, pb = pix0 % P;
  const int hrow = pb / W, wcol = pb % W;         // 16 pixels all in one row
  const float* curb = cur + (size_t)b * P * 64;
  const char* curc = (const char*)curb + cc * 8;
  char* valc = (char*)valA + wave * (4 * PITCHB);

  // A: stage zero-padded 3x3 patches; issue ALL 18 loads first (deep pipelining)
  {
    float2 av[18]; float am[18];
    #pragma unroll
    for (int i = 0; i < 18; i++){
      const int t0 = 2*i, t1 = t0 + 1;
      const int p0 = t0/9, k0 = t0%9, p1 = t1/9, k1 = t1%9;
      int yy0 = hrow + k0/3 - 1, xx0 = wcol + wave*4 + p0 + k0%3 - 1;
      int yy1 = hrow + k1/3 - 1, xx1 = wcol + wave*4 + p1 + k1%3 - 1;
      bool v0 = ((unsigned)yy0 < (unsigned)H) & ((unsigned)xx0 < (unsigned)W);
      bool v1 = ((unsigned)yy1 < (unsigned)H) & ((unsigned)xx1 < (unsigned)W);
      int  i0 = v0 ? (yy0*W + xx0) : 0,  i1 = v1 ? (yy1*W + xx1) : 0;
      int   idx = half ? i1 : i0;
      am[i] = (half ? v1 : v0) ? 1.f : 0.f;
      av[i] = *(const float2*)(curc + (size_t)idx * 256);
    }
    #pragma unroll
    for (int i = 0; i < 18; i++){
      unsigned pk = f2b2(av[i].x * am[i], av[i].y * am[i]);
      const int t0 = 2*i, t1 = t0 + 1;
      const int ob0 = (t0/9)*PITCHB + (t0%9)*128, ob1 = (t1/9)*PITCHB + (t1%9)*128;
      *(unsigned*)(valc + (half ? ob1 : ob0) + cc*4) = pk;
    }
  }
  __syncthreads();

  // B: offset conv [16x576]@[576x32] split over 4 waves (2 col-halves x 2 K-halves)
  {
    const int colw = wave & 1, kh = wave >> 1;
    f32x4 oacc = {0,0,0,0};
    #pragma unroll
    for (int kb = 0; kb < 9; kb++){
      int kk = kh*9 + kb;
      short8 a  = *(const short8*)&valA[c0][kk*32 + quad*8];
      short8 bf = *(const short8*)&owt[(colw*16 + c0)*576 + kk*32 + quad*8];
      oacc = __builtin_amdgcn_mfma_f32_16x16x32_bf16(a, bf, oacc, 0, 0, 0);
    }
    int comp = colw*16 + c0;
    if (comp < 18){
      #pragma unroll
      for (int r = 0; r < 4; r++) offsP[kh][q4 + r][comp] = oacc[r];
    }
  }
  __syncthreads();

  // C0: per-tap bilinear weights + corner byte offsets
  if (tid < 144){
    int p = tid / 9, k = tid % 9;
    int h = hrow, w = wcol + p;
    float oy = offsP[0][p][2*k]     + offsP[1][p][2*k]     + off_bias[LVL*18 + 2*k];
    float ox = offsP[0][p][2*k + 1] + offsP[1][p][2*k + 1] + off_bias[LVL*18 + 2*k + 1];
    float py = (float)(h + k/3 - 1) + oy;
    float px = (float)(w + k%3 - 1) + ox;
    float y0f = floorf(py), x0f = floorf(px);
    float fy = py - y0f, fx = px - x0f;
    int y0 = (int)y0f, x0 = (int)x0f, y1 = y0 + 1, x1 = x0 + 1;
    bool vy0 = (y0 >= 0) & (y0 < H), vy1 = (y1 >= 0) & (y1 < H);
    bool vx0 = (x0 >= 0) & (x0 < W), vx1 = (x1 >= 0) & (x1 < W);
    int y0c = min(max(y0, 0), H-1), y1c = min(max(y1, 0), H-1);
    int x0c = min(max(x0, 0), W-1), x1c = min(max(x1, 0), W-1);
    float gy = 1.f - fy, gx = 1.f - fx;
    tapW[tid] = make_float4((vy0 & vx0) ? gy*gx : 0.f,
                            (vy0 & vx1) ? gy*fx : 0.f,
                            (vy1 & vx0) ? fy*gx : 0.f,
                            (vy1 & vx1) ? fy*fx : 0.f);
    tapI[tid] = make_int4((y0c*W + x0c) << 8, (y0c*W + x1c) << 8,
                          (y1c*W + x0c) << 8, (y1c*W + x1c) << 8);
  }
  __syncthreads();

  // C1: sample; 3 register-batches of 6 taps (24 loads in flight per batch)
  #pragma unroll
  for (int bt = 0; bt < 3; bt++){
    int4 ti[6];
    float2 aa[6][4];
    #pragma unroll
    for (int j = 0; j < 6; j++) ti[j] = tapI[wave*36 + 2*(bt*6 + j) + half];
    #pragma unroll
    for (int j = 0; j < 6; j++){
      aa[j][0] = *(const float2*)(curc + ti[j].x);
      aa[j][1] = *(const float2*)(curc + ti[j].y);
      aa[j][2] = *(const float2*)(curc + ti[j].z);
      aa[j][3] = *(const float2*)(curc + ti[j].w);
    }
    #pragma unroll
    for (int j = 0; j < 6; j++){
      const int i = bt*6 + j;
      float4 wv = tapW[wave*36 + 2*i + half];
      float vx = wv.x*aa[j][0].x + wv.y*aa[j][1].x + wv.z*aa[j][2].x + wv.w*aa[j][3].x;
      float vy = wv.x*aa[j][0].y + wv.y*aa[j][1].y + wv.z*aa[j][2].y + wv.w*aa[j][3].y;
      unsigned pk = f2b2(vx, vy);
      const int t0 = 2*i, t1 = t0 + 1;
      const int ob0 = (t0/9)*PITCHB + (t0%9)*128, ob1 = (t1/9)*PITCHB + (t1%9)*128;
      *(unsigned*)(valc + (half ? ob1 : ob0) + cc*4) = pk;
    }
  }
  __syncthreads();

  // D: deform GEMM [16x576]@[576x64]; wave w takes cols 16w..16w+15; split chain
  const int n = wave*16 + c0;
  float bt2 = dc_bias[LVL*64 + n];
  f32x4 d0 = {bt2, bt2, bt2, bt2}, d1 = {0,0,0,0};
  #pragma unroll
  for (int kb = 0; kb < 9; kb++){
    short8 a  = *(const short8*)&valA[c0][kb*32 + quad*8];
    short8 bf = *(const short8*)&dcw[n*576 + kb*32 + quad*8];
    d0 = __builtin_amdgcn_mfma_f32_16x16x32_bf16(a, bf, d0, 0, 0, 0);
  }
  #pragma unroll
  for (int kb = 9; kb < 18; kb++){
    short8 a  = *(const short8*)&valA[c0][kb*32 + quad*8];
    short8 bf = *(const short8*)&dcw[n*576 + kb*32 + quad*8];
    d1 = __builtin_amdgcn_mfma_f32_16x16x32_bf16(a, bf, d1, 0, 0, 0);
  }
  f32x4 acc;
  #pragma unroll
  for (int r = 0; r < 4; r++) acc[r] = d0[r] + d1[r];
  float* dcb = dc + (size_t)pix0 * 64;
  #pragma unroll
  for (int r = 0; r < 4; r++) dcb[(q4 + r)*64 + n] = acc[r];
  float s = acc[0] + acc[1] + acc[2] + acc[3];
  s += __shfl_xor(s, 16);
  s += __shfl_xor(s, 32);
  if (quad == 0) atomicAdd(&sums[(LVL*16 + (blockIdx.x & 15))*256 + (b << 6) + n], s);
}

// ---- fuse + SE gates + gate + downsample: gates from sums (per block), then
//      (dc*g) @ Wsum_l -> tmp_l (CHW); 2x2 avg pool of gated vals -> cur_{l+1} ----
template<int W, int LVL>
__global__ __launch_bounds__(256) void fuse_gd_k(
    const float* __restrict__ dcv, const float* __restrict__ sums,
    const float* __restrict__ se_w1, const float* __restrict__ se_b1,
    const float* __restrict__ se_w2, const float* __restrict__ se_b2,
    const float* __restrict__ ws_all, float* __restrict__ tmp, float* __restrict__ curn){
  constexpr int P = W * W;
  constexpr bool POOL = (LVL < 3);
  constexpr float invP = 1.f / (float)P;
  __shared__ __align__(16) float fS[64][68];      // gated fp32 values, pad 64->68
  __shared__ __align__(16) float gsh[64];
  const short* wsl = (const short*)(ws_all + OFF_WSUMT) + LVL * 4096;
  const int tid = threadIdx.x, wave = tid >> 6, lane = tid & 63;
  const int c0 = lane & 15, quad = lane >> 4, q4 = quad * 4;
  int b, rp = 0, cs = 0;
  if (POOL){
    constexpr int tilesPerB = P / 64, tilesPerRow = W / 32;
    b = blockIdx.x / tilesPerB;
    int r = blockIdx.x % tilesPerB;
    rp = r / tilesPerRow; cs = r % tilesPerRow;
  } else {
    b = (blockIdx.x * 64) / P;
  }

  // SE gates (redundant per block): slot partials -> mean -> fc-relu-fc-sigmoid
  {
    int sg = tid >> 6, c = tid & 63;
    float part = 0.f;
    #pragma unroll
    for (int s = 0; s < 4; s++) part += sums[(LVL*16 + sg*4 + s)*256 + (b << 6) + c];
    fS[sg][c] = part;
    __syncthreads();
    if (tid < 64){
      int r = tid & 3, j = tid >> 2;
      float hp = 0.f;
      #pragma unroll
      for (int q = 0; q < 4; q++){
        int cq = j*4 + q;
        float m = (fS[0][cq] + fS[1][cq] + fS[2][cq] + fS[3][cq]) * invP;
        hp += m * se_w1[(LVL*4 + r)*64 + cq];
      }
      hp += __shfl_xor(hp, 4);  hp += __shfl_xor(hp, 8);
      hp += __shfl_xor(hp, 16); hp += __shfl_xor(hp, 32);
      float hr = fmaxf(hp + se_b1[LVL*4 + r], 0.f);
      float a = se_b2[LVL*64 + tid];
      #pragma unroll
      for (int r2 = 0; r2 < 4; r2++)
        a += __shfl(hr, r2) * se_w2[(LVL*64 + tid)*4 + r2];
      gsh[tid] = 1.f / (1.f + expf(-a));
    }
    __syncthreads();
  }

  // stage gated fp32 values
  float4 g4 = *(const float4*)&gsh[c0*4];
  #pragma unroll
  for (int i = 0; i < 4; i++){
    int lp = wave*16 + (lane >> 4) + i*4;
    size_t gpix = POOL ? ((size_t)b*P + (size_t)(2*rp + (lp >> 5))*W + cs*32 + (lp & 31))
                       : ((size_t)blockIdx.x*64 + lp);
    float4 d = *(const float4*)&dcv[gpix*64 + c0*4];
    float4 v = make_float4(d.x*g4.x, d.y*g4.y, d.z*g4.z, d.w*g4.w);
    *(float4*)&fS[lp][c0*4] = v;
  }
  __syncthreads();
  // fuse MFMA [16x64]@[64x64] per wave
  f32x4 acc[4] = {{0,0,0,0},{0,0,0,0},{0,0,0,0},{0,0,0,0}};
  #pragma unroll
  for (int kb = 0; kb < 2; kb++){
    float4 lo = *(const float4*)&fS[wave*16 + c0][kb*32 + quad*8];
    float4 hi = *(const float4*)&fS[wave*16 + c0][kb*32 + quad*8 + 4];
    uint4v ua = {f2b2(lo.x, lo.y), f2b2(lo.z, lo.w), f2b2(hi.x, hi.y), f2b2(hi.z, hi.w)};
    short8 a = __builtin_bit_cast(short8, ua);
    #pragma unroll
    for (int t = 0; t < 4; t++){
      short8 bf = *(const short8*)&wsl[(t*16 + c0)*64 + kb*32 + quad*8];
      acc[t] = __builtin_amdgcn_mfma_f32_16x16x32_bf16(a, bf, acc[t], 0, 0, 0);
    }
  }
  #pragma unroll
  for (int t = 0; t < 4; t++){
    int n = t*16 + c0;
    size_t plane = ((size_t)(b << 6) + n) * P;
    size_t pix = POOL ? ((size_t)(2*rp + (wave >> 1))*W + cs*32 + (wave & 1)*16 + q4)
                      : ((size_t)(blockIdx.x*64) - (size_t)b*P + wave*16 + q4);
    *(f32x4*)&tmp[plane + pix] = acc[t];
  }
  // 2x2 avg pool of gated values -> next level input (NHWC)
  if constexpr (POOL){
    int j = tid >> 4, uu = tid & 15;
    float4 p0 = *(const float4*)&fS[2*j][uu*4];
    float4 p1 = *(const float4*)&fS[2*j + 1][uu*4];
    float4 p2 = *(const float4*)&fS[32 + 2*j][uu*4];
    float4 p3 = *(const float4*)&fS[33 + 2*j][uu*4];
    float4 av = make_float4(0.25f*(p0.x + p1.x + p2.x + p3.x),
                            0.25f*(p0.y + p1.y + p2.y + p3.y),
                            0.25f*(p0.z + p1.z + p2.z + p3.z),
                            0.25f*(p0.w + p1.w + p2.w + p3.w));
    *(float4*)&curn[((size_t)b*(P/4) + (size_t)rp*(W/2) + cs*16 + j)*64 + uu*4] = av;
  }
}

// ---- final: 4x bilinear upsample (CHW planes) + sum + fuse bias -> f32 NCHW ----
__global__ void final_k(const float* __restrict__ ws_all, const float* __restrict__ fuse_bias,
                        float* __restrict__ out){
  int i = blockIdx.x * 256 + threadIdx.x;
  int w = i & 127, h = (i >> 7) & 127, o = (i >> 14) & 63, b = i >> 20;
  float acc = fuse_bias[o] + ws_all[OFF_T0 + (((size_t)(b << 6) + o) << 14) + (h << 7) + w];
  const float* tarr[3] = {ws_all + OFF_T1, ws_all + OFF_T2, ws_all + OFF_T3};
  #pragma unroll
  for (int li = 0; li < 3; li++){
    int l = li + 1, Hl = 128 >> l;
    float scale = 1.0f / (float)(1 << l);
    float sy = fminf(fmaxf((h + 0.5f)*scale - 0.5f, 0.f), (float)(Hl - 1));
    float sx = fminf(fmaxf((w + 0.5f)*scale - 0.5f, 0.f), (float)(Hl - 1));
    int y0 = (int)sy, x0 = (int)sx;
    float fy = sy - y0, fx = sx - x0;
    int y1 = min(y0 + 1, Hl - 1), x1 = min(x0 + 1, Hl - 1);
    const float* tb = tarr[li] + (size_t)((b << 6) + o) * Hl * Hl;
    float v00 = tb[y0*Hl + x0], v01 = tb[y0*Hl + x1];
    float v10 = tb[y1*Hl + x0], v11 = tb[y1*Hl + x1];
    acc += (1.f-fy)*((1.f-fx)*v00 + fx*v01) + fy*((1.f-fx)*v10 + fx*v11);
  }
  out[i] = acc;
}

extern "C" void kernel_launch(void* const* d_in, const int* in_sizes, int n_in,
                              void* d_out, int out_size, void* d_ws, size_t ws_size,
                              hipStream_t stream){
  (void)in_sizes; (void)n_in; (void)out_size; (void)ws_size;
  const float* x      = (const float*)d_in[0];
  const float* off_w  = (const float*)d_in[1];
  const float* off_b  = (const float*)d_in[2];
  const float* dc_w   = (const float*)d_in[3];
  const float* dc_b   = (const float*)d_in[4];
  const float* se_w1  = (const float*)d_in[5];
  const float* se_b1  = (const float*)d_in[6];
  const float* se_w2  = (const float*)d_in[7];
  const float* se_b2  = (const float*)d_in[8];
  const float* fuse_w = (const float*)d_in[9];
  const float* fuse_b = (const float*)d_in[10];
  float* out = (float*)d_out;
  float* ws = (float*)d_ws;
  float* cur  = ws + OFF_CUR;
  float* dc   = ws + OFF_DC;
  float* tmp[4] = {ws + OFF_T0, ws + OFF_T1, ws + OFF_T2, ws + OFF_T3};
  float* sums = ws + OFF_SUMS;

  prep_k<<<(303104 + 255)/256, 256, 0, stream>>>(dc_w, off_w, fuse_w, ws);
  cvt_k<<<1024, 256, 0, stream>>>(x, cur);

  // L0
  deform_k<128,0><<<4096, 256, 0, stream>>>(cur, ws, off_b, dc_b, dc, sums);
  fuse_gd_k<128,0><<<1024, 256, 0, stream>>>(dc, sums, se_w1, se_b1, se_w2, se_b2, ws, tmp[0], cur);
  // L1
  deform_k<64,1><<<1024, 256, 0, stream>>>(cur, ws, off_b, dc_b, dc, sums);
  fuse_gd_k<64,1><<<256, 256, 0, stream>>>(dc, sums, se_w1, se_b1, se_w2, se_b2, ws, tmp[1], cur);
  // L2
  deform_k<32,2><<<256, 256, 0, stream>>>(cur, ws, off_b, dc_b, dc, sums);
  fuse_gd_k<32,2><<<64, 256, 0, stream>>>(dc, sums, se_w1, se_b1, se_w2, se_b2, ws, tmp[2], cur);
  // L3
  deform_k<16,3><<<64, 256, 0, stream>>>(cur, ws, off_b, dc_b, dc, sums);
  fuse_gd_k<16,3><<<16, 256, 0, stream>>>(dc, sums, se_w1, se_b1, se_w2, se_b2, ws, tmp[3], nullptr);

  final_k<<<16384, 256, 0, stream>>>(ws, fuse_b, out);
}

// Round 9
// 234.410 us; speedup vs baseline: 1.6799x; 1.1554x over previous
//
#include <hip/hip_runtime.h>
#include <hip/hip_bf16.h>
#include <math.h>

// All reference tensors are float32 -> inputs are const float*, output float*.

constexpr int Bn = 4;          // batch

typedef __attribute__((ext_vector_type(8))) short short8;   // 8 bf16 (4 VGPRs)
typedef __attribute__((ext_vector_type(4))) float f32x4;    // MFMA 16x16 acc
typedef __attribute__((ext_vector_type(4))) unsigned uint4v;

static __device__ __forceinline__ short f2b(float f){
  union { float f; unsigned u; } v; v.f = f;
  unsigned r = v.u + 0x7fffu + ((v.u >> 16) & 1u);   // RNE
  return (short)(r >> 16);
}
// packed f32x2 -> bf16x2 (v_cvt_pk_bf16_f32 on gfx950); low short = x
static __device__ __forceinline__ unsigned f2b2(float x, float y){
  union { __hip_bfloat162 h; unsigned u; } cv;
  cv.h = __float22bfloat162_rn(make_float2(x, y));
  return cv.u;
}
static __device__ __forceinline__ float blo(unsigned u){ return __uint_as_float(u << 16); }
static __device__ __forceinline__ float bhi(unsigned u){ return __uint_as_float(u & 0xffff0000u); }

// ---- workspace layout (float offsets; all multiples of 4 -> 16B aligned) ----
constexpr size_t OFF_CUR   = 0;                         // bf16 [4][16384][64] NHWC (8MB slot)
constexpr size_t OFF_DC    = OFF_CUR  + 4194304;        // f32 4*16384*64 NHWC
constexpr size_t OFF_T0    = OFF_DC   + 4194304;        // fuse outputs, CHW [b][o][p], f32
constexpr size_t OFF_T1    = OFF_T0   + 4194304;
constexpr size_t OFF_T2    = OFF_T1   + 1048576;
constexpr size_t OFF_T3    = OFF_T2   + 262144;
constexpr size_t OFF_WSUMT = OFF_T3   + 65536;          // bf16 [4][64][64]   kdim=c
constexpr size_t OFF_DCWT  = OFF_WSUMT + 8192;          // bf16 [4][64][576]  kdim=k*64+c
constexpr size_t OFF_OWT   = OFF_DCWT  + 73728;         // bf16 [4][32][576]  kdim=k*64+c
constexpr size_t OFF_SUMS  = OFF_OWT   + 36864;         // f32 [4][16 slots][256]

// ---- prep: weights -> bf16 (N-major, kdim=k*64+c), cumulative fuse, zero SE sums ----
__global__ void prep_k(const float* __restrict__ dc_w, const float* __restrict__ off_w,
                       const float* __restrict__ fuse_w, float* __restrict__ ws){
  int i = blockIdx.x * 256 + threadIdx.x;
  short* dcwT  = (short*)(ws + OFF_DCWT);
  short* owT   = (short*)(ws + OFF_OWT);
  short* wsumT = (short*)(ws + OFF_WSUMT);
  if (i < 147456){
    int oc = i / 576, r = i % 576, k = r >> 6, c = r & 63;      // oc = l*64+o
    dcwT[i] = f2b(dc_w[(oc*64 + c)*9 + k]);
  } else if (i < 147456 + 73728){
    int t = i - 147456;
    int lm = t / 576, l = lm >> 5, m = lm & 31, r = t % 576, k = r >> 6, c = r & 63;
    owT[t] = (m < 18) ? f2b(off_w[((l*18 + m)*64 + c)*9 + k]) : (short)0;
  } else if (i < 147456 + 73728 + 16384){
    int t = i - (147456 + 73728);
    int l = t / 4096, r = t % 4096, o = r / 64, c = r % 64;
    float s = 0.f;
    for (int jl = 0; jl <= l; jl++) s += fuse_w[o*256 + jl*64 + c];
    wsumT[t] = f2b(s);
  } else if (i < 147456 + 73728 + 16384 + 65536){
    ws[OFF_SUMS + (i - (147456 + 73728 + 16384))] = 0.f;
  }
}

// ---- convert x: NCHW f32 -> NHWC bf16 via LDS-tiled transpose ----
__global__ __launch_bounds__(256) void cvt_k(const float* __restrict__ x, unsigned* __restrict__ cur){
  __shared__ float t[64][65];
  int tile = blockIdx.x;                 // 1024 tiles: b(4) x 256 pixel-groups
  int b = tile >> 8, p0 = (tile & 255) << 6;
  int tx = threadIdx.x & 63, ty = threadIdx.x >> 6;
  #pragma unroll
  for (int c = ty; c < 64; c += 4)
    t[c][tx] = x[(((size_t)(b << 6) + c) << 14) + p0 + tx];
  __syncthreads();
  int u = threadIdx.x & 31, pr = threadIdx.x >> 5;   // ch-pair, pixel offset
  #pragma unroll
  for (int i = 0; i < 8; i++){
    int pp = pr + i*8;
    unsigned v = f2b2(t[2*u][pp], t[2*u + 1][pp]);
    cur[((size_t)(b << 14) + p0 + pp)*32 + u] = v;
  }
}

// ---- fused: offset conv (MFMA, 4 waves) + bilinear sampling + deform GEMM + SE colsum ----
// 4x4 pixel tile per block (L1-friendly gather footprint); cur is bf16 NHWC (128B/pixel).
template<int H, int LVL>
__global__ __launch_bounds__(256, 6) void deform_k(
    const unsigned* __restrict__ cur, const float* __restrict__ ws_all,
    const float* __restrict__ off_bias, const float* __restrict__ dc_bias,
    float* __restrict__ dc, float* __restrict__ sums){
  constexpr int W = H, P = H * W;
  constexpr int PITCHB = 584 * 2;                 // valA row pitch in bytes (pad 576->584)
  constexpr int TPR = W/4, TPB = P/16;            // tiles per row / per batch
  __shared__ __align__(16) short valA[16][584];   // bf16 [pixel][kdim]
  __shared__ float offsP[2][16][18];              // offset-conv K-partials
  __shared__ float4 tapW[144];                    // bilinear corner weights
  __shared__ int4   tapI[144];                    // corner byte offsets (idx*128)
  const short* owt = (const short*)(ws_all + OFF_OWT) + LVL * 32 * 576;
  const short* dcw = (const short*)(ws_all + OFF_DCWT) + (size_t)LVL * 64 * 576;
  const int tid = threadIdx.x;
  const int wave = tid >> 6, lane = tid & 63;
  const int c0 = lane & 15, quad = lane >> 4, q4 = quad * 4;
  const int half = lane >> 5, cc = lane & 31;     // staging role: ch-pair cc
  const int b = blockIdx.x / TPB;
  const int rr = blockIdx.x % TPB;
  const int hrow = (rr / TPR) * 4, wcol = (rr % TPR) * 4;
  const char* curc = (const char*)(cur + (size_t)b * P * 32) + cc * 4;
  char* valc = (char*)valA + wave * (4 * PITCHB);

  // A: stage zero-padded 3x3 patches (wave = tile row; 2 taps/iter, half-wave each)
  #pragma unroll
  for (int i = 0; i < 18; i++){
    const int t0 = 2*i, t1 = t0 + 1;
    const int p0l = t0/9, k0 = t0%9, p1l = t1/9, k1 = t1%9;   // local pixel 0..3
    int yy0 = hrow + wave + k0/3 - 1, xx0 = wcol + p0l + k0%3 - 1;
    int yy1 = hrow + wave + k1/3 - 1, xx1 = wcol + p1l + k1%3 - 1;
    bool v0 = ((unsigned)yy0 < (unsigned)H) & ((unsigned)xx0 < (unsigned)W);
    bool v1 = ((unsigned)yy1 < (unsigned)H) & ((unsigned)xx1 < (unsigned)W);
    int  i0 = v0 ? (yy0*W + xx0) : 0,  i1 = v1 ? (yy1*W + xx1) : 0;
    int   idx = half ? i1 : i0;
    bool  vv  = half ? v1 : v0;
    unsigned uv = *(const unsigned*)(curc + (size_t)idx * 128);
    uv = vv ? uv : 0u;
    const int ob0 = p0l*PITCHB + k0*128, ob1 = p1l*PITCHB + k1*128;
    *(unsigned*)(valc + (half ? ob1 : ob0) + cc*4) = uv;
  }
  __syncthreads();

  // B: offset conv [16x576]@[576x32] split over 4 waves (2 col-halves x 2 K-halves)
  {
    const int colw = wave & 1, kh = wave >> 1;
    f32x4 oacc = {0,0,0,0};
    #pragma unroll
    for (int kb = 0; kb < 9; kb++){
      int kk = kh*9 + kb;
      short8 a  = *(const short8*)&valA[c0][kk*32 + quad*8];
      short8 bf = *(const short8*)&owt[(colw*16 + c0)*576 + kk*32 + quad*8];
      oacc = __builtin_amdgcn_mfma_f32_16x16x32_bf16(a, bf, oacc, 0, 0, 0);
    }
    int comp = colw*16 + c0;
    if (comp < 18){
      #pragma unroll
      for (int r = 0; r < 4; r++) offsP[kh][q4 + r][comp] = oacc[r];
    }
  }
  __syncthreads();

  // C0: per-tap bilinear weights + corner byte offsets (pixel stride 128B)
  if (tid < 144){
    int p = tid / 9, k = tid % 9;
    int h = hrow + (p >> 2), w = wcol + (p & 3);
    float oy = offsP[0][p][2*k]     + offsP[1][p][2*k]     + off_bias[LVL*18 + 2*k];
    float ox = offsP[0][p][2*k + 1] + offsP[1][p][2*k + 1] + off_bias[LVL*18 + 2*k + 1];
    float py = (float)(h + k/3 - 1) + oy;
    float px = (float)(w + k%3 - 1) + ox;
    float y0f = floorf(py), x0f = floorf(px);
    float fy = py - y0f, fx = px - x0f;
    int y0 = (int)y0f, x0 = (int)x0f, y1 = y0 + 1, x1 = x0 + 1;
    bool vy0 = (y0 >= 0) & (y0 < H), vy1 = (y1 >= 0) & (y1 < H);
    bool vx0 = (x0 >= 0) & (x0 < W), vx1 = (x1 >= 0) & (x1 < W);
    int y0c = min(max(y0, 0), H-1), y1c = min(max(y1, 0), H-1);
    int x0c = min(max(x0, 0), W-1), x1c = min(max(x1, 0), W-1);
    float gy = 1.f - fy, gx = 1.f - fx;
    tapW[tid] = make_float4((vy0 & vx0) ? gy*gx : 0.f,
                            (vy0 & vx1) ? gy*fx : 0.f,
                            (vy1 & vx0) ? fy*gx : 0.f,
                            (vy1 & vx1) ? fy*fx : 0.f);
    tapI[tid] = make_int4((y0c*W + x0c) << 7, (y0c*W + x1c) << 7,
                          (y1c*W + x0c) << 7, (y1c*W + x1c) << 7);
  }
  __syncthreads();

  // C1: sample from bf16 cur; 2 taps/iter (half-wave each), uint (2ch) per lane
  #pragma unroll
  for (int i = 0; i < 18; i++){
    int T = wave*36 + 2*i + half;
    float4 wv = tapW[T];
    int4   ti = tapI[T];
    unsigned u0 = *(const unsigned*)(curc + ti.x);
    unsigned u1 = *(const unsigned*)(curc + ti.y);
    unsigned u2 = *(const unsigned*)(curc + ti.z);
    unsigned u3 = *(const unsigned*)(curc + ti.w);
    float vx = wv.x*blo(u0) + wv.y*blo(u1) + wv.z*blo(u2) + wv.w*blo(u3);
    float vy = wv.x*bhi(u0) + wv.y*bhi(u1) + wv.z*bhi(u2) + wv.w*bhi(u3);
    unsigned pk = f2b2(vx, vy);
    const int t0 = 2*i, t1 = t0 + 1;
    const int ob0 = (t0/9)*PITCHB + (t0%9)*128, ob1 = (t1/9)*PITCHB + (t1%9)*128;
    *(unsigned*)(valc + (half ? ob1 : ob0) + cc*4) = pk;
  }
  __syncthreads();

  // D: deform GEMM [16x576]@[576x64]; wave w takes cols 16w..16w+15; split chain
  const int n = wave*16 + c0;
  float bt2 = dc_bias[LVL*64 + n];
  f32x4 d0 = {bt2, bt2, bt2, bt2}, d1 = {0,0,0,0};
  #pragma unroll
  for (int kb = 0; kb < 9; kb++){
    short8 a  = *(const short8*)&valA[c0][kb*32 + quad*8];
    short8 bf = *(const short8*)&dcw[n*576 + kb*32 + quad*8];
    d0 = __builtin_amdgcn_mfma_f32_16x16x32_bf16(a, bf, d0, 0, 0, 0);
  }
  #pragma unroll
  for (int kb = 9; kb < 18; kb++){
    short8 a  = *(const short8*)&valA[c0][kb*32 + quad*8];
    short8 bf = *(const short8*)&dcw[n*576 + kb*32 + quad*8];
    d1 = __builtin_amdgcn_mfma_f32_16x16x32_bf16(a, bf, d1, 0, 0, 0);
  }
  f32x4 acc;
  #pragma unroll
  for (int r = 0; r < 4; r++) acc[r] = d0[r] + d1[r];
  // C row q4+r = tile pixel (quad, r) -> global pixel (hrow+quad, wcol+r)
  float* dcb = dc + ((size_t)b*P + (size_t)(hrow + quad)*W + wcol)*64;
  #pragma unroll
  for (int r = 0; r < 4; r++) dcb[r*64 + n] = acc[r];
  float s = acc[0] + acc[1] + acc[2] + acc[3];
  s += __shfl_xor(s, 16);
  s += __shfl_xor(s, 32);
  if (quad == 0) atomicAdd(&sums[(LVL*16 + (blockIdx.x & 15))*256 + (b << 6) + n], s);
}

// ---- fuse + SE gates + gate + downsample: gates from sums (per block), then
//      (dc*g) @ Wsum_l -> tmp_l (CHW f32); 2x2 avg pool of gated vals -> bf16 cur_{l+1} ----
template<int W, int LVL>
__global__ __launch_bounds__(256) void fuse_gd_k(
    const float* __restrict__ dcv, const float* __restrict__ sums,
    const float* __restrict__ se_w1, const float* __restrict__ se_b1,
    const float* __restrict__ se_w2, const float* __restrict__ se_b2,
    const float* __restrict__ ws_all, float* __restrict__ tmp, unsigned* __restrict__ curn){
  constexpr int P = W * W;
  constexpr bool POOL = (LVL < 3);
  constexpr float invP = 1.f / (float)P;
  __shared__ __align__(16) float fS[64][68];      // gated fp32 values, pad 64->68
  __shared__ __align__(16) float gsh[64];
  const short* wsl = (const short*)(ws_all + OFF_WSUMT) + LVL * 4096;
  const int tid = threadIdx.x, wave = tid >> 6, lane = tid & 63;
  const int c0 = lane & 15, quad = lane >> 4, q4 = quad * 4;
  int b, rp = 0, cs = 0;
  if (POOL){
    constexpr int tilesPerB = P / 64, tilesPerRow = W / 32;
    b = blockIdx.x / tilesPerB;
    int r = blockIdx.x % tilesPerB;
    rp = r / tilesPerRow; cs = r % tilesPerRow;
  } else {
    b = (blockIdx.x * 64) / P;
  }

  // SE gates (redundant per block): slot partials -> mean -> fc-relu-fc-sigmoid
  {
    int sg = tid >> 6, c = tid & 63;
    float part = 0.f;
    #pragma unroll
    for (int s = 0; s < 4; s++) part += sums[(LVL*16 + sg*4 + s)*256 + (b << 6) + c];
    fS[sg][c] = part;
    __syncthreads();
    if (tid < 64){
      int r = tid & 3, j = tid >> 2;
      float hp = 0.f;
      #pragma unroll
      for (int q = 0; q < 4; q++){
        int cq = j*4 + q;
        float m = (fS[0][cq] + fS[1][cq] + fS[2][cq] + fS[3][cq]) * invP;
        hp += m * se_w1[(LVL*4 + r)*64 + cq];
      }
      hp += __shfl_xor(hp, 4);  hp += __shfl_xor(hp, 8);
      hp += __shfl_xor(hp, 16); hp += __shfl_xor(hp, 32);
      float hr = fmaxf(hp + se_b1[LVL*4 + r], 0.f);
      float a = se_b2[LVL*64 + tid];
      #pragma unroll
      for (int r2 = 0; r2 < 4; r2++)
        a += __shfl(hr, r2) * se_w2[(LVL*64 + tid)*4 + r2];
      gsh[tid] = 1.f / (1.f + expf(-a));
    }
    __syncthreads();
  }

  // stage gated fp32 values
  float4 g4 = *(const float4*)&gsh[c0*4];
  #pragma unroll
  for (int i = 0; i < 4; i++){
    int lp = wave*16 + (lane >> 4) + i*4;
    size_t gpix = POOL ? ((size_t)b*P + (size_t)(2*rp + (lp >> 5))*W + cs*32 + (lp & 31))
                       : ((size_t)blockIdx.x*64 + lp);
    float4 d = *(const float4*)&dcv[gpix*64 + c0*4];
    float4 v = make_float4(d.x*g4.x, d.y*g4.y, d.z*g4.z, d.w*g4.w);
    *(float4*)&fS[lp][c0*4] = v;
  }
  __syncthreads();
  // fuse MFMA [16x64]@[64x64] per wave
  f32x4 acc[4] = {{0,0,0,0},{0,0,0,0},{0,0,0,0},{0,0,0,0}};
  #pragma unroll
  for (int kb = 0; kb < 2; kb++){
    float4 lo = *(const float4*)&fS[wave*16 + c0][kb*32 + quad*8];
    float4 hi = *(const float4*)&fS[wave*16 + c0][kb*32 + quad*8 + 4];
    uint4v ua = {f2b2(lo.x, lo.y), f2b2(lo.z, lo.w), f2b2(hi.x, hi.y), f2b2(hi.z, hi.w)};
    short8 a = __builtin_bit_cast(short8, ua);
    #pragma unroll
    for (int t = 0; t < 4; t++){
      short8 bf = *(const short8*)&wsl[(t*16 + c0)*64 + kb*32 + quad*8];
      acc[t] = __builtin_amdgcn_mfma_f32_16x16x32_bf16(a, bf, acc[t], 0, 0, 0);
    }
  }
  #pragma unroll
  for (int t = 0; t < 4; t++){
    int n = t*16 + c0;
    size_t plane = ((size_t)(b << 6) + n) * P;
    size_t pix = POOL ? ((size_t)(2*rp + (wave >> 1))*W + cs*32 + (wave & 1)*16 + q4)
                      : ((size_t)(blockIdx.x*64) - (size_t)b*P + wave*16 + q4);
    *(f32x4*)&tmp[plane + pix] = acc[t];
  }
  // 2x2 avg pool of gated values -> next level input (bf16 NHWC)
  if constexpr (POOL){
    int j = tid >> 4, uu = tid & 15;
    float4 p0 = *(const float4*)&fS[2*j][uu*4];
    float4 p1 = *(const float4*)&fS[2*j + 1][uu*4];
    float4 p2 = *(const float4*)&fS[32 + 2*j][uu*4];
    float4 p3 = *(const float4*)&fS[33 + 2*j][uu*4];
    float4 av = make_float4(0.25f*(p0.x + p1.x + p2.x + p3.x),
                            0.25f*(p0.y + p1.y + p2.y + p3.y),
                            0.25f*(p0.z + p1.z + p2.z + p3.z),
                            0.25f*(p0.w + p1.w + p2.w + p3.w));
    uint2 pv = make_uint2(f2b2(av.x, av.y), f2b2(av.z, av.w));
    *(uint2*)&curn[((size_t)b*(P/4) + (size_t)rp*(W/2) + cs*16 + j)*32 + uu*2] = pv;
  }
}

// ---- final: 4x bilinear upsample (CHW planes) + sum + fuse bias -> f32 NCHW ----
__global__ void final_k(const float* __restrict__ ws_all, const float* __restrict__ fuse_bias,
                        float* __restrict__ out){
  int i = blockIdx.x * 256 + threadIdx.x;
  int w = i & 127, h = (i >> 7) & 127, o = (i >> 14) & 63, b = i >> 20;
  float acc = fuse_bias[o] + ws_all[OFF_T0 + (((size_t)(b << 6) + o) << 14) + (h << 7) + w];
  const float* tarr[3] = {ws_all + OFF_T1, ws_all + OFF_T2, ws_all + OFF_T3};
  #pragma unroll
  for (int li = 0; li < 3; li++){
    int l = li + 1, Hl = 128 >> l;
    float scale = 1.0f / (float)(1 << l);
    float sy = fminf(fmaxf((h + 0.5f)*scale - 0.5f, 0.f), (float)(Hl - 1));
    float sx = fminf(fmaxf((w + 0.5f)*scale - 0.5f, 0.f), (float)(Hl - 1));
    int y0 = (int)sy, x0 = (int)sx;
    float fy = sy - y0, fx = sx - x0;
    int y1 = min(y0 + 1, Hl - 1), x1 = min(x0 + 1, Hl - 1);
    const float* tb = tarr[li] + (size_t)((b << 6) + o) * Hl * Hl;
    float v00 = tb[y0*Hl + x0], v01 = tb[y0*Hl + x1];
    float v10 = tb[y1*Hl + x0], v11 = tb[y1*Hl + x1];
    acc += (1.f-fy)*((1.f-fx)*v00 + fx*v01) + fy*((1.f-fx)*v10 + fx*v11);
  }
  out[i] = acc;
}

extern "C" void kernel_launch(void* const* d_in, const int* in_sizes, int n_in,
                              void* d_out, int out_size, void* d_ws, size_t ws_size,
                              hipStream_t stream){
  (void)in_sizes; (void)n_in; (void)out_size; (void)ws_size;
  const float* x      = (const float*)d_in[0];
  const float* off_w  = (const float*)d_in[1];
  const float* off_b  = (const float*)d_in[2];
  const float* dc_w   = (const float*)d_in[3];
  const float* dc_b   = (const float*)d_in[4];
  const float* se_w1  = (const float*)d_in[5];
  const float* se_b1  = (const float*)d_in[6];
  const float* se_w2  = (const float*)d_in[7];
  const float* se_b2  = (const float*)d_in[8];
  const float* fuse_w = (const float*)d_in[9];
  const float* fuse_b = (const float*)d_in[10];
  float* out = (float*)d_out;
  float* ws = (float*)d_ws;
  unsigned* cur = (unsigned*)(ws + OFF_CUR);   // bf16 NHWC, 2ch per uint
  float* dc   = ws + OFF_DC;
  float* tmp[4] = {ws + OFF_T0, ws + OFF_T1, ws + OFF_T2, ws + OFF_T3};
  float* sums = ws + OFF_SUMS;

  prep_k<<<(303104 + 255)/256, 256, 0, stream>>>(dc_w, off_w, fuse_w, ws);
  cvt_k<<<1024, 256, 0, stream>>>(x, cur);

  // L0
  deform_k<128,0><<<4096, 256, 0, stream>>>(cur, ws, off_b, dc_b, dc, sums);
  fuse_gd_k<128,0><<<1024, 256, 0, stream>>>(dc, sums, se_w1, se_b1, se_w2, se_b2, ws, tmp[0], cur);
  // L1
  deform_k<64,1><<<1024, 256, 0, stream>>>(cur, ws, off_b, dc_b, dc, sums);
  fuse_gd_k<64,1><<<256, 256, 0, stream>>>(dc, sums, se_w1, se_b1, se_w2, se_b2, ws, tmp[1], cur);
  // L2
  deform_k<32,2><<<256, 256, 0, stream>>>(cur, ws, off_b, dc_b, dc, sums);
  fuse_gd_k<32,2><<<64, 256, 0, stream>>>(dc, sums, se_w1, se_b1, se_w2, se_b2, ws, tmp[2], cur);
  // L3
  deform_k<16,3><<<64, 256, 0, stream>>>(cur, ws, off_b, dc_b, dc, sums);
  fuse_gd_k<16,3><<<16, 256, 0, stream>>>(dc, sums, se_w1, se_b1, se_w2, se_b2, ws, tmp[3], nullptr);

  final_k<<<16384, 256, 0, stream>>>(ws, fuse_b, out);
}